// Round 1
// baseline (10082.762 us; speedup 1.0000x reference)
//
#include <hip/hip_runtime.h>
#include <math.h>

#define BB 32
#define NN 1024
#define KNNK 20
#define PTS (BB*NN)   // 32768

__device__ __forceinline__ float lrelu(float v){ return v >= 0.f ? v : 0.2f*v; }

// ---------------- squared norms per point ----------------
__global__ void sq_kernel(const float* __restrict__ x, int stride, int C, float* __restrict__ xx){
    int pn = blockIdx.x*256 + threadIdx.x;
    if (pn >= PTS) return;
    const float* r = x + (size_t)pn*stride;
    float s = 0.f;
    for (int c = 0; c < C; ++c){ float v = r[c]; s = fmaf(v, v, s); }
    xx[pn] = s;
}

// ---------------- KNN: one block per query point ----------------
template<int C>
__global__ void __launch_bounds__(256) knn_kernel(const float* __restrict__ x, int stride,
                                                  const float* __restrict__ xx, int* __restrict__ idxout){
    constexpr int TJ = 64;
    constexpr int NPART = 4;
    __shared__ float ctr[C];
    __shared__ float tile[TJ][C+1];
    __shared__ float dist[NN];
    __shared__ float part[NPART][TJ];
    __shared__ float wv[4];
    __shared__ int   wi[4];

    const int pn = blockIdx.x;
    const int b = pn >> 10, n = pn & 1023;
    const int tid = threadIdx.x;
    const float* xb = x + (size_t)b * NN * stride;

    for (int c = tid; c < C; c += 256) ctr[c] = xb[(size_t)n*stride + c];
    __syncthreads();
    const float xxi = xx[pn];

    for (int j0 = 0; j0 < NN; j0 += TJ){
        for (int i = tid; i < TJ*C; i += 256){
            int jj = i / C, c = i - jj*C;
            tile[jj][c] = xb[(size_t)(j0+jj)*stride + c];
        }
        __syncthreads();
        {
            int jj = tid & (TJ-1);
            int pt = tid >> 6;
            float s = 0.f;
            for (int c = pt; c < C; c += NPART) s = fmaf(ctr[c], tile[jj][c], s);
            part[pt][jj] = s;
        }
        __syncthreads();
        if (tid < TJ){
            float inner = part[0][tid] + part[1][tid] + part[2][tid] + part[3][tid];
            int j = j0 + tid;
            dist[j] = 2.f*inner - xxi - xx[b*NN + j];
        }
        __syncthreads();
    }

    // top-k by iterative argmax (value desc, index asc on ties)
    int* out = idxout + (size_t)pn * KNNK;
    const int lane = tid & 63;
    const int wav  = tid >> 6;
    for (int t = 0; t < KNNK; ++t){
        float best = -INFINITY; int bi = NN;
        #pragma unroll
        for (int r = 0; r < NN/256; ++r){
            int j = tid + r*256;
            float v = dist[j];
            if (v > best){ best = v; bi = j; }
        }
        #pragma unroll
        for (int off = 32; off > 0; off >>= 1){
            float ov = __shfl_down(best, off);
            int   oi = __shfl_down(bi,  off);
            if (ov > best || (ov == best && oi < bi)){ best = ov; bi = oi; }
        }
        if (lane == 0){ wv[wav] = best; wi[wav] = bi; }
        __syncthreads();
        if (tid == 0){
            float fb = wv[0]; int fi = wi[0];
            #pragma unroll
            for (int w = 1; w < 4; ++w){
                if (wv[w] > fb || (wv[w] == fb && wi[w] < fi)){ fb = wv[w]; fi = wi[w]; }
            }
            out[t] = fi;
            dist[fi] = -INFINITY;
        }
        __syncthreads();
    }
}

// ---------------- edge conv: h = [nbr-ctr, ctr] @ W^T ; max over k + BN stats ----------------
template<int C, int O>
__global__ void __launch_bounds__(256) conv_kernel(const float* __restrict__ xin, int stride,
                                                   const int* __restrict__ idx,
                                                   const float* __restrict__ W,
                                                   float* __restrict__ m_out,
                                                   float* __restrict__ stats){
    constexpr int NP = 256 / O;
    __shared__ __align__(16) float E[NP][KNNK][2*C];
    __shared__ float Ctr[NP][C];
    const int tid = threadIdx.x;
    const int p = tid / O, o = tid % O;
    const int pn0 = blockIdx.x * NP;

    for (int i = tid; i < NP*C; i += 256){
        int pp = i / C, c = i - pp*C;
        Ctr[pp][c] = xin[(size_t)(pn0+pp)*stride + c];
    }
    __syncthreads();
    for (int i = tid; i < NP*KNNK*C; i += 256){
        int pp = i / (KNNK*C); int r = i - pp*(KNNK*C); int kk = r / C; int c = r - kk*C;
        int pn = pn0 + pp; int b = pn >> 10;
        int nb = idx[(size_t)pn*KNNK + kk];
        float nv = xin[((size_t)(b << 10) + nb)*stride + c];
        float cv = Ctr[pp][c];
        E[pp][kk][c]   = nv - cv;
        E[pp][kk][C+c] = cv;
    }
    __syncthreads();

    float h[KNNK];
    #pragma unroll
    for (int kk = 0; kk < KNNK; ++kk) h[kk] = 0.f;

    const float* Wrow = W + (size_t)o*2*C;
    if constexpr ((2*C) % 4 == 0){
        const float4* W4 = reinterpret_cast<const float4*>(Wrow);
        const float4* E4 = reinterpret_cast<const float4*>(&E[p][0][0]);
        #pragma unroll 1
        for (int c4 = 0; c4 < (2*C)/4; ++c4){
            float4 w = W4[c4];
            #pragma unroll
            for (int kk = 0; kk < KNNK; ++kk){
                float4 e = E4[kk*((2*C)/4) + c4];
                h[kk] = fmaf(w.x, e.x, h[kk]);
                h[kk] = fmaf(w.y, e.y, h[kk]);
                h[kk] = fmaf(w.z, e.z, h[kk]);
                h[kk] = fmaf(w.w, e.w, h[kk]);
            }
        }
    } else {
        for (int c = 0; c < 2*C; ++c){
            float w = Wrow[c];
            #pragma unroll
            for (int kk = 0; kk < KNNK; ++kk) h[kk] = fmaf(w, E[p][kk][c], h[kk]);
        }
    }

    float mx = -INFINITY, s1 = 0.f, s2 = 0.f;
    #pragma unroll
    for (int kk = 0; kk < KNNK; ++kk){
        float v = h[kk];
        mx = fmaxf(mx, v); s1 += v; s2 = fmaf(v, v, s2);
    }
    m_out[(size_t)(pn0+p)*O + o] = mx;
    int rep = blockIdx.x & 63;
    atomicAdd(&stats[rep*2*O + o],     s1);
    atomicAdd(&stats[rep*2*O + O + o], s2);
}

// ---------------- finalize BN stats (edge layers) ----------------
__global__ void fin_kernel(const float* __restrict__ stats, int O, float cnt,
                           float* __restrict__ mean, float* __restrict__ invstd){
    int o = threadIdx.x;
    if (o >= O) return;
    float s1 = 0.f, s2 = 0.f;
    for (int r = 0; r < 64; ++r){
        s1 += stats[r*2*O + o];
        s2 += stats[r*2*O + O + o];
    }
    float m = s1 / cnt;
    float v = s2 / cnt - m*m;
    mean[o] = m;
    invstd[o] = rsqrtf(v + 1e-5f);
}

// ---------------- apply BN+LReLU to k-max, write into cat slice ----------------
template<int O>
__global__ void apply_kernel(const float* __restrict__ m_in,
                             const float* __restrict__ mean, const float* __restrict__ invstd,
                             const float* __restrict__ g, const float* __restrict__ bt,
                             float* __restrict__ outbase){
    int i = blockIdx.x*256 + threadIdx.x;
    int pn = i / O, o = i % O;
    float hn = (m_in[i] - mean[o]) * invstd[o] * g[o] + bt[o];
    outbase[(size_t)pn*512 + o] = lrelu(hn);
}

// ---------------- layer 5: cat @ W5^T, stats + max over n (partials) ----------------
__global__ void __launch_bounds__(256) l5_kernel(const float* __restrict__ cat,
                                                 const float* __restrict__ W5,
                                                 float* __restrict__ pmax,
                                                 float* __restrict__ psum,
                                                 float* __restrict__ psq){
    constexpr int TN = 16;
    __shared__ __align__(16) float rows[TN][512];
    const int b  = blockIdx.x;   // 32
    const int ot = blockIdx.y;   // 4
    const int ns = blockIdx.z;   // 8
    const int tid = threadIdx.x;
    const int o = ot*256 + tid;
    const float* cb = cat + ((size_t)b*NN + (size_t)ns*128) * 512;
    const float4* W4 = reinterpret_cast<const float4*>(W5 + (size_t)o*512);

    float mx = -INFINITY, s1 = 0.f, s2 = 0.f;
    for (int t0 = 0; t0 < 128; t0 += TN){
        __syncthreads();
        for (int i = tid; i < TN*512; i += 256){
            rows[i >> 9][i & 511] = cb[(size_t)t0*512 + i];
        }
        __syncthreads();
        float h[TN];
        #pragma unroll
        for (int nn = 0; nn < TN; ++nn) h[nn] = 0.f;
        const float4* R4 = reinterpret_cast<const float4*>(&rows[0][0]);
        #pragma unroll 1
        for (int c4 = 0; c4 < 128; ++c4){
            float4 w = W4[c4];
            #pragma unroll
            for (int nn = 0; nn < TN; ++nn){
                float4 e = R4[nn*128 + c4];
                h[nn] = fmaf(w.x, e.x, h[nn]);
                h[nn] = fmaf(w.y, e.y, h[nn]);
                h[nn] = fmaf(w.z, e.z, h[nn]);
                h[nn] = fmaf(w.w, e.w, h[nn]);
            }
        }
        #pragma unroll
        for (int nn = 0; nn < TN; ++nn){
            float v = h[nn];
            mx = fmaxf(mx, v); s1 += v; s2 = fmaf(v, v, s2);
        }
    }
    size_t pi = ((size_t)b*8 + ns)*1024 + o;
    pmax[pi] = mx; psum[pi] = s1; psq[pi] = s2;
}

__global__ void fin5_kernel(const float* __restrict__ pmax, const float* __restrict__ psum,
                            const float* __restrict__ psq,
                            const float* __restrict__ g, const float* __restrict__ bt,
                            float* __restrict__ out){
    int o = blockIdx.x*256 + threadIdx.x; // 1024 total
    float s1 = 0.f, s2 = 0.f;
    for (int r = 0; r < 256; ++r){
        s1 += psum[(size_t)r*1024 + o];
        s2 += psq [(size_t)r*1024 + o];
    }
    float m  = s1 / 32768.f;
    float v  = s2 / 32768.f - m*m;
    float is = rsqrtf(v + 1e-5f);
    float gg = g[o], bb2 = bt[o];
    for (int b = 0; b < 32; ++b){
        float mx = -INFINITY;
        #pragma unroll
        for (int ns = 0; ns < 8; ++ns) mx = fmaxf(mx, pmax[((size_t)b*8 + ns)*1024 + o]);
        float hn = (mx - m) * is * gg + bb2;
        out[(size_t)b*1024 + o] = lrelu(hn);
    }
}

extern "C" void kernel_launch(void* const* d_in, const int* in_sizes, int n_in,
                              void* d_out, int out_size, void* d_ws, size_t ws_size,
                              hipStream_t stream) {
    (void)in_sizes; (void)n_in; (void)out_size; (void)ws_size;
    const float* x  = (const float*)d_in[0];
    const float* W1 = (const float*)d_in[1];  const float* g1 = (const float*)d_in[2];  const float* b1 = (const float*)d_in[3];
    const float* W2 = (const float*)d_in[4];  const float* g2 = (const float*)d_in[5];  const float* b2 = (const float*)d_in[6];
    const float* W3 = (const float*)d_in[7];  const float* g3 = (const float*)d_in[8];  const float* b3 = (const float*)d_in[9];
    const float* W4 = (const float*)d_in[10]; const float* g4 = (const float*)d_in[11]; const float* b4 = (const float*)d_in[12];
    const float* W5 = (const float*)d_in[13]; const float* g5 = (const float*)d_in[14]; const float* b5 = (const float*)d_in[15];
    float* out = (float*)d_out;

    char* wsp = (char*)d_ws;
    float* cat    = (float*)wsp; wsp += (size_t)PTS*512*4;   // 67,108,864
    float* m_tmp  = (float*)wsp; wsp += (size_t)PTS*256*4;   // 33,554,432
    int*   idx    = (int*)  wsp; wsp += (size_t)PTS*KNNK*4;  //  2,621,440
    float* xx     = (float*)wsp; wsp += (size_t)PTS*4;       //    524,288
    float* stats  = (float*)wsp; wsp += (size_t)64*2*256*4;  //    131,072
    float* mean   = (float*)wsp; wsp += 1024*4;
    float* invstd = (float*)wsp; wsp += 1024*4;
    float* pmax   = (float*)wsp; wsp += (size_t)256*1024*4;  //  1,048,576
    float* psum   = (float*)wsp; wsp += (size_t)256*1024*4;
    float* psq    = (float*)wsp; wsp += (size_t)256*1024*4;

    const float cntE = (float)(PTS*KNNK);

    // ---- Layer 1: C=3 -> O=64, cat offset 0 ----
    sq_kernel<<<PTS/256, 256, 0, stream>>>(x, 3, 3, xx);
    knn_kernel<3><<<PTS, 256, 0, stream>>>(x, 3, xx, idx);
    hipMemsetAsync(stats, 0, 64*2*64*4, stream);
    conv_kernel<3,64><<<PTS/4, 256, 0, stream>>>(x, 3, idx, W1, m_tmp, stats);
    fin_kernel<<<1, 64, 0, stream>>>(stats, 64, cntE, mean, invstd);
    apply_kernel<64><<<PTS*64/256, 256, 0, stream>>>(m_tmp, mean, invstd, g1, b1, cat + 0);

    // ---- Layer 2: C=64 -> O=64, cat offset 64 ----
    sq_kernel<<<PTS/256, 256, 0, stream>>>(cat + 0, 512, 64, xx);
    knn_kernel<64><<<PTS, 256, 0, stream>>>(cat + 0, 512, xx, idx);
    hipMemsetAsync(stats, 0, 64*2*64*4, stream);
    conv_kernel<64,64><<<PTS/4, 256, 0, stream>>>(cat + 0, 512, idx, W2, m_tmp, stats);
    fin_kernel<<<1, 64, 0, stream>>>(stats, 64, cntE, mean, invstd);
    apply_kernel<64><<<PTS*64/256, 256, 0, stream>>>(m_tmp, mean, invstd, g2, b2, cat + 64);

    // ---- Layer 3: C=64 -> O=128, cat offset 128 ----
    sq_kernel<<<PTS/256, 256, 0, stream>>>(cat + 64, 512, 64, xx);
    knn_kernel<64><<<PTS, 256, 0, stream>>>(cat + 64, 512, xx, idx);
    hipMemsetAsync(stats, 0, 64*2*128*4, stream);
    conv_kernel<64,128><<<PTS/2, 256, 0, stream>>>(cat + 64, 512, idx, W3, m_tmp, stats);
    fin_kernel<<<1, 128, 0, stream>>>(stats, 128, cntE, mean, invstd);
    apply_kernel<128><<<PTS*128/256, 256, 0, stream>>>(m_tmp, mean, invstd, g3, b3, cat + 128);

    // ---- Layer 4: C=128 -> O=256, cat offset 256 ----
    sq_kernel<<<PTS/256, 256, 0, stream>>>(cat + 128, 512, 128, xx);
    knn_kernel<128><<<PTS, 256, 0, stream>>>(cat + 128, 512, xx, idx);
    hipMemsetAsync(stats, 0, 64*2*256*4, stream);
    conv_kernel<128,256><<<PTS, 256, 0, stream>>>(cat + 128, 512, idx, W4, m_tmp, stats);
    fin_kernel<<<1, 256, 0, stream>>>(stats, 256, cntE, mean, invstd);
    apply_kernel<256><<<PTS*256/256, 256, 0, stream>>>(m_tmp, mean, invstd, g4, b4, cat + 256);

    // ---- Layer 5: (B,N,512) @ (1024,512)^T, BN over (B,N), max over N ----
    l5_kernel<<<dim3(32, 4, 8), 256, 0, stream>>>(cat, W5, pmax, psum, psq);
    fin5_kernel<<<4, 256, 0, stream>>>(pmax, psum, psq, g5, b5, out);
}

// Round 2
// 4222.474 us; speedup vs baseline: 2.3879x; 2.3879x over previous
//
#include <hip/hip_runtime.h>
#include <math.h>

#define BB 32
#define NN 1024
#define KNNK 20
#define PTS (BB*NN)   // 32768

__device__ __forceinline__ float lrelu(float v){ return v >= 0.f ? v : 0.2f*v; }

// ---------------- squared norms per point ----------------
__global__ void sq_kernel(const float* __restrict__ x, int stride, int C, float* __restrict__ xx){
    int pn = blockIdx.x*256 + threadIdx.x;
    if (pn >= PTS) return;
    const float* r = x + (size_t)pn*stride;
    float s = 0.f;
    for (int c = 0; c < C; ++c){ float v = r[c]; s = fmaf(v, v, s); }
    xx[pn] = s;
}

// ---------------- fused KNN: dist GEMM tile + wave-per-row top-k ----------------
// block = 8 query rows of one batch; 256 threads.
template<int C>
__global__ void __launch_bounds__(256) knn2_kernel(const float* __restrict__ x, int stride,
                                                   const float* __restrict__ xx, int* __restrict__ idxout){
    constexpr int RB = 8;                      // rows per block
    constexpr int CT = 128;                    // col tile
    constexpr int KC = (C < 32 ? C : 32);      // k chunk
    __shared__ float As[RB][C+1];
    __shared__ float xxs[NN];
    __shared__ float Bl[KC][CT+4];
    __shared__ float dist_s[RB][NN+8];         // row stride 1032 floats

    const int tid = threadIdx.x;
    const int bt = blockIdx.x >> 7;            // batch (128 row-tiles per batch)
    const int rt = blockIdx.x & 127;
    const int i0 = rt*RB;
    const float* xb = x + (size_t)bt*NN*stride;

    for (int i = tid; i < RB*C; i += 256){
        int r = i / C, c = i - r*C;
        As[r][c] = xb[(size_t)(i0+r)*stride + c];
    }
    for (int j = tid; j < NN; j += 256) xxs[j] = xx[bt*NN + j];
    __syncthreads();

    const int r  = tid & 7;
    const int cg = tid >> 3;                   // 0..31, cols cg*4..+3 of tile

    for (int jt = 0; jt < NN/CT; ++jt){
        float acc0 = 0.f, acc1 = 0.f, acc2 = 0.f, acc3 = 0.f;
        for (int kc = 0; kc < C; kc += KC){
            __syncthreads();
            for (int i = tid; i < KC*CT; i += 256){
                int k = i % KC, j = i / KC;
                Bl[k][j] = xb[(size_t)(jt*CT + j)*stride + kc + k];
            }
            __syncthreads();
            #pragma unroll
            for (int k = 0; k < KC; ++k){
                float a = As[r][kc + k];
                float4 b4 = *(const float4*)&Bl[k][cg*4];
                acc0 = fmaf(a, b4.x, acc0);
                acc1 = fmaf(a, b4.y, acc1);
                acc2 = fmaf(a, b4.z, acc2);
                acc3 = fmaf(a, b4.w, acc3);
            }
        }
        float xi = xxs[i0 + r];
        int jb = jt*CT + cg*4;
        float4 dv;
        dv.x = 2.f*acc0 - xi - xxs[jb+0];
        dv.y = 2.f*acc1 - xi - xxs[jb+1];
        dv.z = 2.f*acc2 - xi - xxs[jb+2];
        dv.w = 2.f*acc3 - xi - xxs[jb+3];
        *(float4*)&dist_s[r][jb] = dv;
    }
    __syncthreads();

    // top-k: wave wv handles rows wv*2, wv*2+1
    const int wv = tid >> 6, lane = tid & 63;
    for (int rr = wv*2; rr < wv*2 + 2; ++rr){
        float v[16];
        #pragma unroll
        for (int i2 = 0; i2 < 16; ++i2) v[i2] = dist_s[rr][i2*64 + lane];
        int* orow = idxout + ((size_t)(bt*NN) + i0 + rr)*KNNK;
        for (int t = 0; t < KNNK; ++t){
            float bv = v[0]; int bs = 0;
            #pragma unroll
            for (int i2 = 1; i2 < 16; ++i2){ if (v[i2] > bv){ bv = v[i2]; bs = i2; } }
            int bj = bs*64 + lane;
            #pragma unroll
            for (int m = 32; m; m >>= 1){
                float ov = __shfl_xor(bv, m);
                int   oj = __shfl_xor(bj, m);
                if (ov > bv || (ov == bv && oj < bj)){ bv = ov; bj = oj; }
            }
            int clr = ((bj & 63) == lane) ? (bj >> 6) : -1;
            #pragma unroll
            for (int i2 = 0; i2 < 16; ++i2) if (i2 == clr) v[i2] = -INFINITY;
            if (lane == 0) orow[t] = bj;
        }
    }
}

// ---------------- G GEMMs: G1 = X @ W[:, :C]^T ; Gd = X @ (W[:,C:]-W[:, :C])^T ----------------
// per batch-group of 8192 points. 64x64 tiles, thread 4x4.
template<int C, int O>
__global__ void __launch_bounds__(256) gemmG_kernel(const float* __restrict__ x, int stride,
                                                    const float* __restrict__ W,
                                                    float* __restrict__ G1, float* __restrict__ Gd){
    constexpr int KC = (C < 32 ? C : 32);
    __shared__ float Xl [KC][68];
    __shared__ float W1l[KC][68];
    __shared__ float W2l[KC][68];
    const int tid = threadIdx.x;
    const int r0 = blockIdx.x * 64;
    const int o0 = blockIdx.y * 64;
    const int rt = tid & 15, ct = tid >> 4;

    float a1[4][4] = {{0.f}}, a2[4][4] = {{0.f}};
    for (int kc = 0; kc < C; kc += KC){
        __syncthreads();
        for (int i = tid; i < KC*64; i += 256){
            int k = i % KC, rr = i / KC;
            Xl [k][rr] = x[(size_t)(r0+rr)*stride + kc + k];
            W1l[k][rr] = W[(size_t)(o0+rr)*(2*C) + kc + k];
            W2l[k][rr] = W[(size_t)(o0+rr)*(2*C) + C + kc + k];
        }
        __syncthreads();
        #pragma unroll
        for (int k = 0; k < KC; ++k){
            float4 xa = *(const float4*)&Xl [k][rt*4];
            float4 w1 = *(const float4*)&W1l[k][ct*4];
            float4 w2 = *(const float4*)&W2l[k][ct*4];
            float xv[4] = {xa.x, xa.y, xa.z, xa.w};
            #pragma unroll
            for (int i = 0; i < 4; ++i){
                a1[i][0] = fmaf(xv[i], w1.x, a1[i][0]);
                a1[i][1] = fmaf(xv[i], w1.y, a1[i][1]);
                a1[i][2] = fmaf(xv[i], w1.z, a1[i][2]);
                a1[i][3] = fmaf(xv[i], w1.w, a1[i][3]);
                a2[i][0] = fmaf(xv[i], w2.x, a2[i][0]);
                a2[i][1] = fmaf(xv[i], w2.y, a2[i][1]);
                a2[i][2] = fmaf(xv[i], w2.z, a2[i][2]);
                a2[i][3] = fmaf(xv[i], w2.w, a2[i][3]);
            }
        }
    }
    #pragma unroll
    for (int i = 0; i < 4; ++i){
        size_t row = (size_t)(r0 + rt*4 + i);
        float4 g1v = make_float4(a1[i][0], a1[i][1], a1[i][2], a1[i][3]);
        float4 gdv = make_float4(a2[i][0]-a1[i][0], a2[i][1]-a1[i][1],
                                 a2[i][2]-a1[i][2], a2[i][3]-a1[i][3]);
        *(float4*)&G1[row*O + o0 + ct*4] = g1v;
        *(float4*)&Gd[row*O + o0 + ct*4] = gdv;
    }
}

// ---------------- gather: per (point,o) max/sum/sumsq over k via G1 rows ----------------
template<int O>
__global__ void __launch_bounds__(256) gather_kernel(const float* __restrict__ G1,
                                                     const float* __restrict__ Gd,
                                                     const int* __restrict__ idxg, int bgbase,
                                                     float* __restrict__ catslice,
                                                     float* __restrict__ stats){
    constexpr int PP = 256 / O;
    constexpr int NP = 16;
    __shared__ int nbs[NP][KNNK];
    const int tid = threadIdx.x;
    const int p0 = blockIdx.x * NP;           // local point base within bg
    for (int i = tid; i < NP*KNNK; i += 256){
        int pp = i / KNNK, kk = i - pp*KNNK;
        int pl = p0 + pp;
        int nb = idxg[(size_t)(bgbase + pl)*KNNK + kk];
        nbs[pp][kk] = ((pl >> 10) << 10) + nb;   // local row within bg's G1
    }
    __syncthreads();
    const int o  = tid % O;
    const int pq = tid / O;
    float s1 = 0.f, s2 = 0.f;
    for (int pp = pq; pp < NP; pp += PP){
        int pl = p0 + pp;
        float d = Gd[(size_t)pl*O + o];
        float mx = -INFINITY, ls = 0.f, lq = 0.f;
        #pragma unroll
        for (int kk = 0; kk < KNNK; ++kk){
            float g = G1[(size_t)nbs[pp][kk]*O + o];
            mx = fmaxf(mx, g);
            ls += g;
            lq = fmaf(g, g, lq);
        }
        s1 += ls + 20.f*d;
        s2 += lq + 2.f*d*ls + 20.f*d*d;
        catslice[(size_t)(bgbase + pl)*512 + o] = mx + d;   // pre-BN k-max
    }
    int rep = blockIdx.x & 63;
    atomicAdd(&stats[rep*2*O + o],     s1);
    atomicAdd(&stats[rep*2*O + O + o], s2);
}

// ---------------- finalize BN stats ----------------
__global__ void fin_kernel(const float* __restrict__ stats, int O, float cnt,
                           float* __restrict__ mean, float* __restrict__ invstd){
    int o = threadIdx.x;
    if (o >= O) return;
    float s1 = 0.f, s2 = 0.f;
    for (int r = 0; r < 64; ++r){
        s1 += stats[r*2*O + o];
        s2 += stats[r*2*O + O + o];
    }
    float m = s1 / cnt;
    float v = s2 / cnt - m*m;
    mean[o] = m;
    invstd[o] = rsqrtf(v + 1e-5f);
}

// ---------------- apply BN+LReLU in place on cat slice ----------------
template<int O>
__global__ void apply_kernel(float* __restrict__ catslice,
                             const float* __restrict__ mean, const float* __restrict__ invstd,
                             const float* __restrict__ g, const float* __restrict__ bt){
    int i = blockIdx.x*256 + threadIdx.x;
    int pn = i / O, o = i - pn*O;
    float* p = &catslice[(size_t)pn*512 + o];
    float hn = (*p - mean[o]) * invstd[o] * g[o] + bt[o];
    *p = lrelu(hn);
}

// ---------------- layer 5: cat @ W5^T, stats + max over n (partials) ----------------
__global__ void __launch_bounds__(256) l5_kernel(const float* __restrict__ cat,
                                                 const float* __restrict__ W5,
                                                 float* __restrict__ pmax,
                                                 float* __restrict__ psum,
                                                 float* __restrict__ psq){
    constexpr int TN = 16;
    __shared__ __align__(16) float rows[TN][512];
    const int b  = blockIdx.x;   // 32
    const int ot = blockIdx.y;   // 4
    const int ns = blockIdx.z;   // 8
    const int tid = threadIdx.x;
    const int o = ot*256 + tid;
    const float* cb = cat + ((size_t)b*NN + (size_t)ns*128) * 512;
    const float4* W4 = reinterpret_cast<const float4*>(W5 + (size_t)o*512);

    float mx = -INFINITY, s1 = 0.f, s2 = 0.f;
    for (int t0 = 0; t0 < 128; t0 += TN){
        __syncthreads();
        for (int i = tid; i < TN*512; i += 256){
            rows[i >> 9][i & 511] = cb[(size_t)t0*512 + i];
        }
        __syncthreads();
        float h[TN];
        #pragma unroll
        for (int nn = 0; nn < TN; ++nn) h[nn] = 0.f;
        const float4* R4 = reinterpret_cast<const float4*>(&rows[0][0]);
        #pragma unroll 1
        for (int c4 = 0; c4 < 128; ++c4){
            float4 w = W4[c4];
            #pragma unroll
            for (int nn = 0; nn < TN; ++nn){
                float4 e = R4[nn*128 + c4];
                h[nn] = fmaf(w.x, e.x, h[nn]);
                h[nn] = fmaf(w.y, e.y, h[nn]);
                h[nn] = fmaf(w.z, e.z, h[nn]);
                h[nn] = fmaf(w.w, e.w, h[nn]);
            }
        }
        #pragma unroll
        for (int nn = 0; nn < TN; ++nn){
            float v = h[nn];
            mx = fmaxf(mx, v); s1 += v; s2 = fmaf(v, v, s2);
        }
    }
    size_t pi = ((size_t)b*8 + ns)*1024 + o;
    pmax[pi] = mx; psum[pi] = s1; psq[pi] = s2;
}

__global__ void fin5_kernel(const float* __restrict__ pmax, const float* __restrict__ psum,
                            const float* __restrict__ psq,
                            const float* __restrict__ g, const float* __restrict__ bt,
                            float* __restrict__ out){
    int o = blockIdx.x*256 + threadIdx.x; // 1024 total
    float s1 = 0.f, s2 = 0.f;
    for (int r = 0; r < 256; ++r){
        s1 += psum[(size_t)r*1024 + o];
        s2 += psq [(size_t)r*1024 + o];
    }
    float m  = s1 / 32768.f;
    float v  = s2 / 32768.f - m*m;
    float is = rsqrtf(v + 1e-5f);
    float gg = g[o], bb2 = bt[o];
    for (int b = 0; b < 32; ++b){
        float mx = -INFINITY;
        #pragma unroll
        for (int ns = 0; ns < 8; ++ns) mx = fmaxf(mx, pmax[((size_t)b*8 + ns)*1024 + o]);
        float hn = (mx - m) * is * gg + bb2;
        out[(size_t)b*1024 + o] = lrelu(hn);
    }
}

extern "C" void kernel_launch(void* const* d_in, const int* in_sizes, int n_in,
                              void* d_out, int out_size, void* d_ws, size_t ws_size,
                              hipStream_t stream) {
    (void)in_sizes; (void)n_in; (void)out_size; (void)ws_size;
    const float* x  = (const float*)d_in[0];
    const float* W1 = (const float*)d_in[1];  const float* g1 = (const float*)d_in[2];  const float* b1 = (const float*)d_in[3];
    const float* W2 = (const float*)d_in[4];  const float* g2 = (const float*)d_in[5];  const float* b2 = (const float*)d_in[6];
    const float* W3 = (const float*)d_in[7];  const float* g3 = (const float*)d_in[8];  const float* b3 = (const float*)d_in[9];
    const float* W4 = (const float*)d_in[10]; const float* g4 = (const float*)d_in[11]; const float* b4 = (const float*)d_in[12];
    const float* W5 = (const float*)d_in[13]; const float* g5 = (const float*)d_in[14]; const float* b5 = (const float*)d_in[15];
    float* out = (float*)d_out;

    char* wsp = (char*)d_ws;
    float* cat    = (float*)wsp; wsp += (size_t)PTS*512*4;     // 67 MB
    float* G1     = (float*)wsp; wsp += (size_t)8192*256*4;    // 8.4 MB
    float* Gd     = (float*)wsp; wsp += (size_t)8192*256*4;    // 8.4 MB
    int*   idx    = (int*)  wsp; wsp += (size_t)PTS*KNNK*4;    // 2.6 MB
    float* xx     = (float*)wsp; wsp += (size_t)PTS*4;
    float* stats  = (float*)wsp; wsp += (size_t)64*2*256*4;
    float* mean   = (float*)wsp; wsp += 1024*4;
    float* invstd = (float*)wsp; wsp += 1024*4;
    float* pmax   = (float*)wsp; wsp += (size_t)256*1024*4;
    float* psum   = (float*)wsp; wsp += (size_t)256*1024*4;
    float* psq    = (float*)wsp; wsp += (size_t)256*1024*4;

    const float cntE = (float)(PTS*KNNK);

    // ---- Layer 1: C=3 -> O=64, cat offset 0 ----
    sq_kernel<<<PTS/256, 256, 0, stream>>>(x, 3, 3, xx);
    knn2_kernel<3><<<PTS/8, 256, 0, stream>>>(x, 3, xx, idx);
    hipMemsetAsync(stats, 0, 64*2*256*4, stream);
    for (int bg = 0; bg < 4; ++bg){
        gemmG_kernel<3,64><<<dim3(128,1), 256, 0, stream>>>(x + (size_t)bg*8192*3, 3, W1, G1, Gd);
        gather_kernel<64><<<512, 256, 0, stream>>>(G1, Gd, idx, bg*8192, cat + 0, stats);
    }
    fin_kernel<<<1, 64, 0, stream>>>(stats, 64, cntE, mean, invstd);
    apply_kernel<64><<<PTS*64/256, 256, 0, stream>>>(cat + 0, mean, invstd, g1, b1);

    // ---- Layer 2: C=64 -> O=64, cat offset 64 ----
    sq_kernel<<<PTS/256, 256, 0, stream>>>(cat + 0, 512, 64, xx);
    knn2_kernel<64><<<PTS/8, 256, 0, stream>>>(cat + 0, 512, xx, idx);
    hipMemsetAsync(stats, 0, 64*2*256*4, stream);
    for (int bg = 0; bg < 4; ++bg){
        gemmG_kernel<64,64><<<dim3(128,1), 256, 0, stream>>>(cat + 0 + (size_t)bg*8192*512, 512, W2, G1, Gd);
        gather_kernel<64><<<512, 256, 0, stream>>>(G1, Gd, idx, bg*8192, cat + 64, stats);
    }
    fin_kernel<<<1, 64, 0, stream>>>(stats, 64, cntE, mean, invstd);
    apply_kernel<64><<<PTS*64/256, 256, 0, stream>>>(cat + 64, mean, invstd, g2, b2);

    // ---- Layer 3: C=64 -> O=128, cat offset 128 ----
    sq_kernel<<<PTS/256, 256, 0, stream>>>(cat + 64, 512, 64, xx);
    knn2_kernel<64><<<PTS/8, 256, 0, stream>>>(cat + 64, 512, xx, idx);
    hipMemsetAsync(stats, 0, 64*2*256*4, stream);
    for (int bg = 0; bg < 4; ++bg){
        gemmG_kernel<64,128><<<dim3(128,2), 256, 0, stream>>>(cat + 64 + (size_t)bg*8192*512, 512, W3, G1, Gd);
        gather_kernel<128><<<512, 256, 0, stream>>>(G1, Gd, idx, bg*8192, cat + 128, stats);
    }
    fin_kernel<<<1, 128, 0, stream>>>(stats, 128, cntE, mean, invstd);
    apply_kernel<128><<<PTS*128/256, 256, 0, stream>>>(cat + 128, mean, invstd, g3, b3);

    // ---- Layer 4: C=128 -> O=256, cat offset 256 ----
    sq_kernel<<<PTS/256, 256, 0, stream>>>(cat + 128, 512, 128, xx);
    knn2_kernel<128><<<PTS/8, 256, 0, stream>>>(cat + 128, 512, xx, idx);
    hipMemsetAsync(stats, 0, 64*2*256*4, stream);
    for (int bg = 0; bg < 4; ++bg){
        gemmG_kernel<128,256><<<dim3(128,4), 256, 0, stream>>>(cat + 128 + (size_t)bg*8192*512, 512, W4, G1, Gd);
        gather_kernel<256><<<512, 256, 0, stream>>>(G1, Gd, idx, bg*8192, cat + 256, stats);
    }
    fin_kernel<<<1, 256, 0, stream>>>(stats, 256, cntE, mean, invstd);
    apply_kernel<256><<<PTS*256/256, 256, 0, stream>>>(cat + 256, mean, invstd, g4, b4);

    // ---- Layer 5: (B,N,512) @ (1024,512)^T, BN over (B,N), max over N ----
    l5_kernel<<<dim3(32, 4, 8), 256, 0, stream>>>(cat, W5, pmax, psum, psq);
    fin5_kernel<<<4, 256, 0, stream>>>(pmax, psum, psq, g5, b5, out);
}

// Round 3
// 2325.626 us; speedup vs baseline: 4.3355x; 1.8156x over previous
//
#include <hip/hip_runtime.h>
#include <math.h>

#define BB 32
#define NN 1024
#define KNNK 20
#define PTS (BB*NN)   // 32768

__device__ __forceinline__ float lrelu(float v){ return v >= 0.f ? v : 0.2f*v; }

// ---------------- squared norms per point ----------------
__global__ void sq_kernel(const float* __restrict__ x, int stride, int C, float* __restrict__ xx){
    int pn = blockIdx.x*256 + threadIdx.x;
    if (pn >= PTS) return;
    const float* r = x + (size_t)pn*stride;
    float s = 0.f;
    for (int c = 0; c < C; ++c){ float v = r[c]; s = fmaf(v, v, s); }
    xx[pn] = s;
}

// ---------------- distance GEMM: D = 2*X@X^T - xx_i - xx_j (4-batch chunk) ----------------
// 64x64 tile, 4x4 per thread. grid (16,16,4), block 256.
template<int C>
__global__ void __launch_bounds__(256) dist_kernel(const float* __restrict__ x, int stride,
                                                   const float* __restrict__ xx,
                                                   float* __restrict__ D, int bc){
    constexpr int KC = (C < 32 ? C : 32);
    __shared__ float As[KC][68];
    __shared__ float Bs[KC][68];
    const int tid = threadIdx.x;
    const int i0 = blockIdx.x * 64;
    const int j0 = blockIdx.y * 64;
    const int bl = blockIdx.z;            // 0..3 within chunk
    const int b  = bc*4 + bl;
    const float* xb = x + (size_t)b*NN*stride;
    const int rt = tid & 15, ct = tid >> 4;
    float acc[4][4] = {{0.f}};

    for (int kc = 0; kc < C; kc += KC){
        __syncthreads();
        if constexpr (KC % 4 == 0){
            for (int i = tid; i < 64*(KC/4); i += 256){
                int kq = i % (KC/4), rr = i / (KC/4);
                float4 va = *(const float4*)&xb[(size_t)(i0+rr)*stride + kc + kq*4];
                As[kq*4+0][rr]=va.x; As[kq*4+1][rr]=va.y; As[kq*4+2][rr]=va.z; As[kq*4+3][rr]=va.w;
                float4 vb = *(const float4*)&xb[(size_t)(j0+rr)*stride + kc + kq*4];
                Bs[kq*4+0][rr]=vb.x; Bs[kq*4+1][rr]=vb.y; Bs[kq*4+2][rr]=vb.z; Bs[kq*4+3][rr]=vb.w;
            }
        } else {
            for (int i = tid; i < 64*KC; i += 256){
                int k = i % KC, rr = i / KC;
                As[k][rr] = xb[(size_t)(i0+rr)*stride + kc + k];
                Bs[k][rr] = xb[(size_t)(j0+rr)*stride + kc + k];
            }
        }
        __syncthreads();
        #pragma unroll
        for (int k = 0; k < KC; ++k){
            float4 a = *(const float4*)&As[k][rt*4];
            float4 bv= *(const float4*)&Bs[k][ct*4];
            float av[4]={a.x,a.y,a.z,a.w};
            float bw[4]={bv.x,bv.y,bv.z,bv.w};
            #pragma unroll
            for (int i = 0; i < 4; ++i)
                #pragma unroll
                for (int j = 0; j < 4; ++j)
                    acc[i][j] = fmaf(av[i], bw[j], acc[i][j]);
        }
    }
    const float* xxb = xx + b*NN;
    float xi[4], xj[4];
    #pragma unroll
    for (int i=0;i<4;++i) xi[i] = xxb[i0 + rt*4 + i];
    #pragma unroll
    for (int j=0;j<4;++j) xj[j] = xxb[j0 + ct*4 + j];
    #pragma unroll
    for (int i=0;i<4;++i){
        float4 dv;
        dv.x = 2.f*acc[i][0] - xi[i] - xj[0];
        dv.y = 2.f*acc[i][1] - xi[i] - xj[1];
        dv.z = 2.f*acc[i][2] - xi[i] - xj[2];
        dv.w = 2.f*acc[i][3] - xi[i] - xj[3];
        *(float4*)&D[((size_t)bl*NN + i0 + rt*4 + i)*NN + j0 + ct*4] = dv;
    }
}

// ---------------- top-k over D rows: wave per row, register argmax ----------------
__global__ void __launch_bounds__(256) topk_kernel(const float* __restrict__ D,
                                                   int* __restrict__ idxout, int bc){
    const int tid = threadIdx.x;
    const int wv = tid >> 6, lane = tid & 63;
    const int rid = blockIdx.x*4 + wv;       // 0..4095 within chunk
    const float* drow = D + (size_t)rid * NN;
    float v[16];
    #pragma unroll
    for (int i2 = 0; i2 < 16; ++i2) v[i2] = drow[i2*64 + lane];
    int* orow = idxout + ((size_t)bc*4096 + rid) * KNNK;
    for (int t = 0; t < KNNK; ++t){
        float bv = v[0]; int bs = 0;
        #pragma unroll
        for (int i2 = 1; i2 < 16; ++i2){ if (v[i2] > bv){ bv = v[i2]; bs = i2; } }
        int bj = bs*64 + lane;
        #pragma unroll
        for (int m = 32; m; m >>= 1){
            float ov = __shfl_xor(bv, m);
            int   oj = __shfl_xor(bj, m);
            if (ov > bv || (ov == bv && oj < bj)){ bv = ov; bj = oj; }
        }
        int clr = ((bj & 63) == lane) ? (bj >> 6) : -1;
        #pragma unroll
        for (int i2 = 0; i2 < 16; ++i2) if (i2 == clr) v[i2] = -INFINITY;
        if (lane == 0) orow[t] = bj;
    }
}

// ---------------- G GEMMs: G1 = X @ W[:, :C]^T ; Gd = X @ (W[:,C:]-W[:, :C])^T ----------------
template<int C, int O>
__global__ void __launch_bounds__(256) gemmG_kernel(const float* __restrict__ x, int stride,
                                                    const float* __restrict__ W,
                                                    float* __restrict__ G1, float* __restrict__ Gd){
    constexpr int KC = (C < 32 ? C : 32);
    __shared__ float Xl [KC][68];
    __shared__ float W1l[KC][68];
    __shared__ float W2l[KC][68];
    const int tid = threadIdx.x;
    const int r0 = blockIdx.x * 64;
    const int o0 = blockIdx.y * 64;
    const int rt = tid & 15, ct = tid >> 4;

    float a1[4][4] = {{0.f}}, a2[4][4] = {{0.f}};
    for (int kc = 0; kc < C; kc += KC){
        __syncthreads();
        for (int i = tid; i < KC*64; i += 256){
            int k = i % KC, rr = i / KC;
            Xl [k][rr] = x[(size_t)(r0+rr)*stride + kc + k];
            W1l[k][rr] = W[(size_t)(o0+rr)*(2*C) + kc + k];
            W2l[k][rr] = W[(size_t)(o0+rr)*(2*C) + C + kc + k];
        }
        __syncthreads();
        #pragma unroll
        for (int k = 0; k < KC; ++k){
            float4 xa = *(const float4*)&Xl [k][rt*4];
            float4 w1 = *(const float4*)&W1l[k][ct*4];
            float4 w2 = *(const float4*)&W2l[k][ct*4];
            float xv[4] = {xa.x, xa.y, xa.z, xa.w};
            #pragma unroll
            for (int i = 0; i < 4; ++i){
                a1[i][0] = fmaf(xv[i], w1.x, a1[i][0]);
                a1[i][1] = fmaf(xv[i], w1.y, a1[i][1]);
                a1[i][2] = fmaf(xv[i], w1.z, a1[i][2]);
                a1[i][3] = fmaf(xv[i], w1.w, a1[i][3]);
                a2[i][0] = fmaf(xv[i], w2.x, a2[i][0]);
                a2[i][1] = fmaf(xv[i], w2.y, a2[i][1]);
                a2[i][2] = fmaf(xv[i], w2.z, a2[i][2]);
                a2[i][3] = fmaf(xv[i], w2.w, a2[i][3]);
            }
        }
    }
    #pragma unroll
    for (int i = 0; i < 4; ++i){
        size_t row = (size_t)(r0 + rt*4 + i);
        float4 g1v = make_float4(a1[i][0], a1[i][1], a1[i][2], a1[i][3]);
        float4 gdv = make_float4(a2[i][0]-a1[i][0], a2[i][1]-a1[i][1],
                                 a2[i][2]-a1[i][2], a2[i][3]-a1[i][3]);
        *(float4*)&G1[row*O + o0 + ct*4] = g1v;
        *(float4*)&Gd[row*O + o0 + ct*4] = gdv;
    }
}

// ---------------- gather: per (point,o) max/sum/sumsq over k via G1 rows ----------------
template<int O>
__global__ void __launch_bounds__(256) gather_kernel(const float* __restrict__ G1,
                                                     const float* __restrict__ Gd,
                                                     const int* __restrict__ idxg, int bgbase,
                                                     float* __restrict__ catslice,
                                                     float* __restrict__ stats){
    constexpr int PP = 256 / O;
    constexpr int NP = 16;
    __shared__ int nbs[NP][KNNK];
    const int tid = threadIdx.x;
    const int p0 = blockIdx.x * NP;
    for (int i = tid; i < NP*KNNK; i += 256){
        int pp = i / KNNK, kk = i - pp*KNNK;
        int pl = p0 + pp;
        int nb = idxg[(size_t)(bgbase + pl)*KNNK + kk];
        nbs[pp][kk] = ((pl >> 10) << 10) + nb;
    }
    __syncthreads();
    const int o  = tid % O;
    const int pq = tid / O;
    float s1 = 0.f, s2 = 0.f;
    for (int pp = pq; pp < NP; pp += PP){
        int pl = p0 + pp;
        float d = Gd[(size_t)pl*O + o];
        float mx = -INFINITY, ls = 0.f, lq = 0.f;
        #pragma unroll
        for (int kk = 0; kk < KNNK; ++kk){
            float g = G1[(size_t)nbs[pp][kk]*O + o];
            mx = fmaxf(mx, g);
            ls += g;
            lq = fmaf(g, g, lq);
        }
        s1 += ls + 20.f*d;
        s2 += lq + 2.f*d*ls + 20.f*d*d;
        catslice[(size_t)(bgbase + pl)*512 + o] = mx + d;
    }
    int rep = blockIdx.x & 63;
    atomicAdd(&stats[rep*2*O + o],     s1);
    atomicAdd(&stats[rep*2*O + O + o], s2);
}

// ---------------- finalize BN stats ----------------
__global__ void fin_kernel(const float* __restrict__ stats, int O, float cnt,
                           float* __restrict__ mean, float* __restrict__ invstd){
    int o = threadIdx.x;
    if (o >= O) return;
    float s1 = 0.f, s2 = 0.f;
    for (int r = 0; r < 64; ++r){
        s1 += stats[r*2*O + o];
        s2 += stats[r*2*O + O + o];
    }
    float m = s1 / cnt;
    float v = s2 / cnt - m*m;
    mean[o] = m;
    invstd[o] = rsqrtf(v + 1e-5f);
}

// ---------------- apply BN+LReLU in place on cat slice ----------------
template<int O>
__global__ void apply_kernel(float* __restrict__ catslice,
                             const float* __restrict__ mean, const float* __restrict__ invstd,
                             const float* __restrict__ g, const float* __restrict__ bt){
    int i = blockIdx.x*256 + threadIdx.x;
    int pn = i / O, o = i - pn*O;
    float* p = &catslice[(size_t)pn*512 + o];
    float hn = (*p - mean[o]) * invstd[o] * g[o] + bt[o];
    *p = lrelu(hn);
}

// ---------------- layer 5: 128x128 tile GEMM + fused max/stats epilogue ----------------
// grid (256, 8): rowtile (= b*8+ns), coltile. block 256, 8x8 per thread.
__global__ void __launch_bounds__(256) l5_kernel(const float* __restrict__ cat,
                                                 const float* __restrict__ W5,
                                                 float* __restrict__ pmax,
                                                 float* __restrict__ psum,
                                                 float* __restrict__ psq){
    __shared__ float smem[2*32*132];
    float (*As)[132] = (float(*)[132])smem;
    float (*Bs)[132] = (float(*)[132])(smem + 32*132);
    const int tid = threadIdx.x;
    const int r0 = blockIdx.x * 128;
    const int o0 = blockIdx.y * 128;
    const int rt = tid & 15, ct = tid >> 4;
    float acc[8][8] = {{0.f}};

    for (int kc = 0; kc < 512; kc += 32){
        __syncthreads();
        for (int i = tid; i < 128*8; i += 256){
            int kq = i & 7, rr = i >> 3;
            float4 va = *(const float4*)&cat[(size_t)(r0+rr)*512 + kc + kq*4];
            As[kq*4+0][rr]=va.x; As[kq*4+1][rr]=va.y; As[kq*4+2][rr]=va.z; As[kq*4+3][rr]=va.w;
            float4 vb = *(const float4*)&W5[(size_t)(o0+rr)*512 + kc + kq*4];
            Bs[kq*4+0][rr]=vb.x; Bs[kq*4+1][rr]=vb.y; Bs[kq*4+2][rr]=vb.z; Bs[kq*4+3][rr]=vb.w;
        }
        __syncthreads();
        #pragma unroll
        for (int k = 0; k < 32; ++k){
            float4 a0 = *(const float4*)&As[k][rt*8];
            float4 a1 = *(const float4*)&As[k][rt*8+4];
            float4 b0 = *(const float4*)&Bs[k][ct*8];
            float4 b1 = *(const float4*)&Bs[k][ct*8+4];
            float av[8]={a0.x,a0.y,a0.z,a0.w,a1.x,a1.y,a1.z,a1.w};
            float bw[8]={b0.x,b0.y,b0.z,b0.w,b1.x,b1.y,b1.z,b1.w};
            #pragma unroll
            for (int i=0;i<8;++i)
                #pragma unroll
                for (int j=0;j<8;++j)
                    acc[i][j] = fmaf(av[i], bw[j], acc[i][j]);
        }
    }
    // epilogue: per-column (o) max/sum/sumsq over the 128 rows of this tile
    __syncthreads();
    float* red = smem;                 // reuse (8448 floats >= 3*2064)
    constexpr int RS = 129;
    constexpr int S  = 16*129;
    #pragma unroll
    for (int j = 0; j < 8; ++j){
        float mx=-INFINITY, s1=0.f, s2=0.f;
        #pragma unroll
        for (int i=0;i<8;++i){ float h=acc[i][j]; mx=fmaxf(mx,h); s1+=h; s2=fmaf(h,h,s2); }
        red[0*S + rt*RS + ct*8 + j] = mx;
        red[1*S + rt*RS + ct*8 + j] = s1;
        red[2*S + rt*RS + ct*8 + j] = s2;
    }
    __syncthreads();
    if (tid < 128){
        float mx=-INFINITY, s1=0.f, s2=0.f;
        #pragma unroll
        for (int r=0;r<16;++r){
            mx = fmaxf(mx, red[0*S + r*RS + tid]);
            s1 += red[1*S + r*RS + tid];
            s2 += red[2*S + r*RS + tid];
        }
        size_t pi = (size_t)blockIdx.x*1024 + o0 + tid;
        pmax[pi]=mx; psum[pi]=s1; psq[pi]=s2;
    }
}

__global__ void fin5_kernel(const float* __restrict__ pmax, const float* __restrict__ psum,
                            const float* __restrict__ psq,
                            const float* __restrict__ g, const float* __restrict__ bt,
                            float* __restrict__ out){
    int o = blockIdx.x*256 + threadIdx.x; // 1024 total
    float s1 = 0.f, s2 = 0.f;
    for (int r = 0; r < 256; ++r){
        s1 += psum[(size_t)r*1024 + o];
        s2 += psq [(size_t)r*1024 + o];
    }
    float m  = s1 / 32768.f;
    float v  = s2 / 32768.f - m*m;
    float is = rsqrtf(v + 1e-5f);
    float gg = g[o], bb2 = bt[o];
    for (int b = 0; b < 32; ++b){
        float mx = -INFINITY;
        #pragma unroll
        for (int ns = 0; ns < 8; ++ns) mx = fmaxf(mx, pmax[((size_t)b*8 + ns)*1024 + o]);
        float hn = (mx - m) * is * gg + bb2;
        out[(size_t)b*1024 + o] = lrelu(hn);
    }
}

extern "C" void kernel_launch(void* const* d_in, const int* in_sizes, int n_in,
                              void* d_out, int out_size, void* d_ws, size_t ws_size,
                              hipStream_t stream) {
    (void)in_sizes; (void)n_in; (void)out_size; (void)ws_size;
    const float* x  = (const float*)d_in[0];
    const float* W1 = (const float*)d_in[1];  const float* g1 = (const float*)d_in[2];  const float* b1 = (const float*)d_in[3];
    const float* W2 = (const float*)d_in[4];  const float* g2 = (const float*)d_in[5];  const float* b2 = (const float*)d_in[6];
    const float* W3 = (const float*)d_in[7];  const float* g3 = (const float*)d_in[8];  const float* b3 = (const float*)d_in[9];
    const float* W4 = (const float*)d_in[10]; const float* g4 = (const float*)d_in[11]; const float* b4 = (const float*)d_in[12];
    const float* W5 = (const float*)d_in[13]; const float* g5 = (const float*)d_in[14]; const float* b5 = (const float*)d_in[15];
    float* out = (float*)d_out;

    char* wsp = (char*)d_ws;
    float* cat    = (float*)wsp; wsp += (size_t)PTS*512*4;       // 67 MB
    float* Dbuf   = (float*)wsp; wsp += (size_t)4*NN*NN*4;       // 16.8 MB (4-batch chunk)
    float* G1     = (float*)wsp; wsp += (size_t)8192*256*4;      // 8.4 MB
    float* Gd     = (float*)wsp; wsp += (size_t)8192*256*4;      // 8.4 MB
    int*   idx    = (int*)  wsp; wsp += (size_t)PTS*KNNK*4;      // 2.6 MB
    float* xx     = (float*)wsp; wsp += (size_t)PTS*4;
    float* stats  = (float*)wsp; wsp += (size_t)64*2*256*4;
    float* mean   = (float*)wsp; wsp += 1024*4;
    float* invstd = (float*)wsp; wsp += 1024*4;
    float* pmax   = (float*)wsp; wsp += (size_t)256*1024*4;
    float* psum   = (float*)wsp; wsp += (size_t)256*1024*4;
    float* psq    = (float*)wsp; wsp += (size_t)256*1024*4;

    const float cntE = (float)(PTS*KNNK);

    // ---- Layer 1: C=3 -> O=64, cat offset 0 ----
    sq_kernel<<<PTS/256, 256, 0, stream>>>(x, 3, 3, xx);
    for (int bc = 0; bc < 8; ++bc){
        dist_kernel<3><<<dim3(16,16,4), 256, 0, stream>>>(x, 3, xx, Dbuf, bc);
        topk_kernel<<<1024, 256, 0, stream>>>(Dbuf, idx, bc);
    }
    hipMemsetAsync(stats, 0, 64*2*256*4, stream);
    for (int bg = 0; bg < 4; ++bg){
        gemmG_kernel<3,64><<<dim3(128,1), 256, 0, stream>>>(x + (size_t)bg*8192*3, 3, W1, G1, Gd);
        gather_kernel<64><<<512, 256, 0, stream>>>(G1, Gd, idx, bg*8192, cat + 0, stats);
    }
    fin_kernel<<<1, 64, 0, stream>>>(stats, 64, cntE, mean, invstd);
    apply_kernel<64><<<PTS*64/256, 256, 0, stream>>>(cat + 0, mean, invstd, g1, b1);

    // ---- Layer 2: C=64 -> O=64, cat offset 64 ----
    sq_kernel<<<PTS/256, 256, 0, stream>>>(cat + 0, 512, 64, xx);
    for (int bc = 0; bc < 8; ++bc){
        dist_kernel<64><<<dim3(16,16,4), 256, 0, stream>>>(cat + 0, 512, xx, Dbuf, bc);
        topk_kernel<<<1024, 256, 0, stream>>>(Dbuf, idx, bc);
    }
    hipMemsetAsync(stats, 0, 64*2*256*4, stream);
    for (int bg = 0; bg < 4; ++bg){
        gemmG_kernel<64,64><<<dim3(128,1), 256, 0, stream>>>(cat + 0 + (size_t)bg*8192*512, 512, W2, G1, Gd);
        gather_kernel<64><<<512, 256, 0, stream>>>(G1, Gd, idx, bg*8192, cat + 64, stats);
    }
    fin_kernel<<<1, 64, 0, stream>>>(stats, 64, cntE, mean, invstd);
    apply_kernel<64><<<PTS*64/256, 256, 0, stream>>>(cat + 64, mean, invstd, g2, b2);

    // ---- Layer 3: C=64 -> O=128, cat offset 128 ----
    sq_kernel<<<PTS/256, 256, 0, stream>>>(cat + 64, 512, 64, xx);
    for (int bc = 0; bc < 8; ++bc){
        dist_kernel<64><<<dim3(16,16,4), 256, 0, stream>>>(cat + 64, 512, xx, Dbuf, bc);
        topk_kernel<<<1024, 256, 0, stream>>>(Dbuf, idx, bc);
    }
    hipMemsetAsync(stats, 0, 64*2*256*4, stream);
    for (int bg = 0; bg < 4; ++bg){
        gemmG_kernel<64,128><<<dim3(128,2), 256, 0, stream>>>(cat + 64 + (size_t)bg*8192*512, 512, W3, G1, Gd);
        gather_kernel<128><<<512, 256, 0, stream>>>(G1, Gd, idx, bg*8192, cat + 128, stats);
    }
    fin_kernel<<<1, 128, 0, stream>>>(stats, 128, cntE, mean, invstd);
    apply_kernel<128><<<PTS*128/256, 256, 0, stream>>>(cat + 128, mean, invstd, g3, b3);

    // ---- Layer 4: C=128 -> O=256, cat offset 256 ----
    sq_kernel<<<PTS/256, 256, 0, stream>>>(cat + 128, 512, 128, xx);
    for (int bc = 0; bc < 8; ++bc){
        dist_kernel<128><<<dim3(16,16,4), 256, 0, stream>>>(cat + 128, 512, xx, Dbuf, bc);
        topk_kernel<<<1024, 256, 0, stream>>>(Dbuf, idx, bc);
    }
    hipMemsetAsync(stats, 0, 64*2*256*4, stream);
    for (int bg = 0; bg < 4; ++bg){
        gemmG_kernel<128,256><<<dim3(128,4), 256, 0, stream>>>(cat + 128 + (size_t)bg*8192*512, 512, W4, G1, Gd);
        gather_kernel<256><<<512, 256, 0, stream>>>(G1, Gd, idx, bg*8192, cat + 256, stats);
    }
    fin_kernel<<<1, 256, 0, stream>>>(stats, 256, cntE, mean, invstd);
    apply_kernel<256><<<PTS*256/256, 256, 0, stream>>>(cat + 256, mean, invstd, g4, b4);

    // ---- Layer 5: (B,N,512) @ (1024,512)^T, BN over (B,N), max over N ----
    l5_kernel<<<dim3(256, 8), 256, 0, stream>>>(cat, W5, pmax, psum, psq);
    fin5_kernel<<<4, 256, 0, stream>>>(pmax, psum, psq, g5, b5, out);
}

// Round 4
// 1562.859 us; speedup vs baseline: 6.4515x; 1.4881x over previous
//
#include <hip/hip_runtime.h>
#include <math.h>

#define BB 32
#define NN 1024
#define KNNK 20
#define PTS (BB*NN)   // 32768

typedef __attribute__((ext_vector_type(8))) short short8;
typedef __attribute__((ext_vector_type(4))) float f32x4;

__device__ __forceinline__ float lrelu(float v){ return v >= 0.f ? v : 0.2f*v; }

__device__ __forceinline__ unsigned short f2b(float x){
    union { float f; unsigned u; } c; c.f = x;
    unsigned r = c.u + 0x7FFFu + ((c.u >> 16) & 1u);
    return (unsigned short)(r >> 16);
}

// ---------------- squared norms per point ----------------
__global__ void sq_kernel(const float* __restrict__ x, int stride, int C, float* __restrict__ xx){
    int pn = blockIdx.x*256 + threadIdx.x;
    if (pn >= PTS) return;
    const float* r = x + (size_t)pn*stride;
    float s = 0.f;
    for (int c = 0; c < C; ++c){ float v = r[c]; s = fmaf(v, v, s); }
    xx[pn] = s;
}

// ---------------- distance GEMM: D = 2*X@X^T - xx_i - xx_j (8-batch chunk) ----------------
// 64x64 tile, 4x4 per thread. grid (16,16,8), block 256. NUMERICS UNCHANGED vs R3.
template<int C>
__global__ void __launch_bounds__(256) dist_kernel(const float* __restrict__ x, int stride,
                                                   const float* __restrict__ xx,
                                                   float* __restrict__ D, int bc){
    constexpr int KC = (C < 32 ? C : 32);
    __shared__ float As[KC][68];
    __shared__ float Bs[KC][68];
    const int tid = threadIdx.x;
    const int i0 = blockIdx.x * 64;
    const int j0 = blockIdx.y * 64;
    const int bl = blockIdx.z;            // 0..7 within chunk
    const int b  = bc*8 + bl;
    const float* xb = x + (size_t)b*NN*stride;
    const int rt = tid & 15, ct = tid >> 4;
    float acc[4][4] = {{0.f}};

    for (int kc = 0; kc < C; kc += KC){
        __syncthreads();
        if constexpr (KC % 4 == 0){
            for (int i = tid; i < 64*(KC/4); i += 256){
                int kq = i % (KC/4), rr = i / (KC/4);
                float4 va = *(const float4*)&xb[(size_t)(i0+rr)*stride + kc + kq*4];
                As[kq*4+0][rr]=va.x; As[kq*4+1][rr]=va.y; As[kq*4+2][rr]=va.z; As[kq*4+3][rr]=va.w;
                float4 vb = *(const float4*)&xb[(size_t)(j0+rr)*stride + kc + kq*4];
                Bs[kq*4+0][rr]=vb.x; Bs[kq*4+1][rr]=vb.y; Bs[kq*4+2][rr]=vb.z; Bs[kq*4+3][rr]=vb.w;
            }
        } else {
            for (int i = tid; i < 64*KC; i += 256){
                int k = i % KC, rr = i / KC;
                As[k][rr] = xb[(size_t)(i0+rr)*stride + kc + k];
                Bs[k][rr] = xb[(size_t)(j0+rr)*stride + kc + k];
            }
        }
        __syncthreads();
        #pragma unroll
        for (int k = 0; k < KC; ++k){
            float4 a = *(const float4*)&As[k][rt*4];
            float4 bv= *(const float4*)&Bs[k][ct*4];
            float av[4]={a.x,a.y,a.z,a.w};
            float bw[4]={bv.x,bv.y,bv.z,bv.w};
            #pragma unroll
            for (int i = 0; i < 4; ++i)
                #pragma unroll
                for (int j = 0; j < 4; ++j)
                    acc[i][j] = fmaf(av[i], bw[j], acc[i][j]);
        }
    }
    const float* xxb = xx + b*NN;
    float xi[4], xj[4];
    #pragma unroll
    for (int i=0;i<4;++i) xi[i] = xxb[i0 + rt*4 + i];
    #pragma unroll
    for (int j=0;j<4;++j) xj[j] = xxb[j0 + ct*4 + j];
    #pragma unroll
    for (int i=0;i<4;++i){
        float4 dv;
        dv.x = 2.f*acc[i][0] - xi[i] - xj[0];
        dv.y = 2.f*acc[i][1] - xi[i] - xj[1];
        dv.z = 2.f*acc[i][2] - xi[i] - xj[2];
        dv.w = 2.f*acc[i][3] - xi[i] - xj[3];
        *(float4*)&D[((size_t)bl*NN + i0 + rt*4 + i)*NN + j0 + ct*4] = dv;
    }
}

// ---------------- top-k over D rows: wave per row, register argmax ----------------
__global__ void __launch_bounds__(256) topk_kernel(const float* __restrict__ D,
                                                   int* __restrict__ idxout, int bc){
    const int tid = threadIdx.x;
    const int wv = tid >> 6, lane = tid & 63;
    const int rid = blockIdx.x*4 + wv;       // 0..8191 within chunk
    const float* drow = D + (size_t)rid * NN;
    float v[16];
    #pragma unroll
    for (int i2 = 0; i2 < 16; ++i2) v[i2] = drow[i2*64 + lane];
    int* orow = idxout + ((size_t)bc*8192 + rid) * KNNK;
    for (int t = 0; t < KNNK; ++t){
        float bv = v[0]; int bs = 0;
        #pragma unroll
        for (int i2 = 1; i2 < 16; ++i2){ if (v[i2] > bv){ bv = v[i2]; bs = i2; } }
        int bj = bs*64 + lane;
        #pragma unroll
        for (int m = 32; m; m >>= 1){
            float ov = __shfl_xor(bv, m);
            int   oj = __shfl_xor(bj, m);
            if (ov > bv || (ov == bv && oj < bj)){ bv = ov; bj = oj; }
        }
        int clr = ((bj & 63) == lane) ? (bj >> 6) : -1;
        #pragma unroll
        for (int i2 = 0; i2 < 16; ++i2) if (i2 == clr) v[i2] = -INFINITY;
        if (lane == 0) orow[t] = bj;
    }
}

// ---------------- G GEMMs: G1 = X @ W[:, :C]^T ; Gd = X @ (W[:,C:]-W[:, :C])^T ----------------
template<int C, int O>
__global__ void __launch_bounds__(256) gemmG_kernel(const float* __restrict__ x, int stride,
                                                    const float* __restrict__ W,
                                                    float* __restrict__ G1, float* __restrict__ Gd){
    constexpr int KC = (C < 32 ? C : 32);
    __shared__ float Xl [KC][68];
    __shared__ float W1l[KC][68];
    __shared__ float W2l[KC][68];
    const int tid = threadIdx.x;
    const int r0 = blockIdx.x * 64;
    const int o0 = blockIdx.y * 64;
    const int rt = tid & 15, ct = tid >> 4;

    float a1[4][4] = {{0.f}}, a2[4][4] = {{0.f}};
    for (int kc = 0; kc < C; kc += KC){
        __syncthreads();
        for (int i = tid; i < KC*64; i += 256){
            int k = i % KC, rr = i / KC;
            Xl [k][rr] = x[(size_t)(r0+rr)*stride + kc + k];
            W1l[k][rr] = W[(size_t)(o0+rr)*(2*C) + kc + k];
            W2l[k][rr] = W[(size_t)(o0+rr)*(2*C) + C + kc + k];
        }
        __syncthreads();
        #pragma unroll
        for (int k = 0; k < KC; ++k){
            float4 xa = *(const float4*)&Xl [k][rt*4];
            float4 w1 = *(const float4*)&W1l[k][ct*4];
            float4 w2 = *(const float4*)&W2l[k][ct*4];
            float xv[4] = {xa.x, xa.y, xa.z, xa.w};
            #pragma unroll
            for (int i = 0; i < 4; ++i){
                a1[i][0] = fmaf(xv[i], w1.x, a1[i][0]);
                a1[i][1] = fmaf(xv[i], w1.y, a1[i][1]);
                a1[i][2] = fmaf(xv[i], w1.z, a1[i][2]);
                a1[i][3] = fmaf(xv[i], w1.w, a1[i][3]);
                a2[i][0] = fmaf(xv[i], w2.x, a2[i][0]);
                a2[i][1] = fmaf(xv[i], w2.y, a2[i][1]);
                a2[i][2] = fmaf(xv[i], w2.z, a2[i][2]);
                a2[i][3] = fmaf(xv[i], w2.w, a2[i][3]);
            }
        }
    }
    #pragma unroll
    for (int i = 0; i < 4; ++i){
        size_t row = (size_t)(r0 + rt*4 + i);
        float4 g1v = make_float4(a1[i][0], a1[i][1], a1[i][2], a1[i][3]);
        float4 gdv = make_float4(a2[i][0]-a1[i][0], a2[i][1]-a1[i][1],
                                 a2[i][2]-a1[i][2], a2[i][3]-a1[i][3]);
        *(float4*)&G1[row*O + o0 + ct*4] = g1v;
        *(float4*)&Gd[row*O + o0 + ct*4] = gdv;
    }
}

// ---------------- gather: per (point,o) max/sum/sumsq over k via G1 rows ----------------
template<int O>
__global__ void __launch_bounds__(256) gather_kernel(const float* __restrict__ G1,
                                                     const float* __restrict__ Gd,
                                                     const int* __restrict__ idxg, int bgbase,
                                                     float* __restrict__ catslice,
                                                     float* __restrict__ stats){
    constexpr int PP = 256 / O;
    constexpr int NP = 16;
    __shared__ int nbs[NP][KNNK];
    const int tid = threadIdx.x;
    const int p0 = blockIdx.x * NP;
    for (int i = tid; i < NP*KNNK; i += 256){
        int pp = i / KNNK, kk = i - pp*KNNK;
        int pl = p0 + pp;
        int nb = idxg[(size_t)(bgbase + pl)*KNNK + kk];
        nbs[pp][kk] = ((pl >> 10) << 10) + nb;
    }
    __syncthreads();
    const int o  = tid % O;
    const int pq = tid / O;
    float s1 = 0.f, s2 = 0.f;
    for (int pp = pq; pp < NP; pp += PP){
        int pl = p0 + pp;
        float d = Gd[(size_t)pl*O + o];
        float mx = -INFINITY, ls = 0.f, lq = 0.f;
        #pragma unroll
        for (int kk = 0; kk < KNNK; ++kk){
            float g = G1[(size_t)nbs[pp][kk]*O + o];
            mx = fmaxf(mx, g);
            ls += g;
            lq = fmaf(g, g, lq);
        }
        s1 += ls + 20.f*d;
        s2 += lq + 2.f*d*ls + 20.f*d*d;
        catslice[(size_t)(bgbase + pl)*512 + o] = mx + d;
    }
    int rep = blockIdx.x & 63;
    atomicAdd(&stats[rep*2*O + o],     s1);
    atomicAdd(&stats[rep*2*O + O + o], s2);
}

// ---------------- finalize BN stats ----------------
__global__ void fin_kernel(const float* __restrict__ stats, int O, float cnt,
                           float* __restrict__ mean, float* __restrict__ invstd){
    int o = threadIdx.x;
    if (o >= O) return;
    float s1 = 0.f, s2 = 0.f;
    for (int r = 0; r < 64; ++r){
        s1 += stats[r*2*O + o];
        s2 += stats[r*2*O + O + o];
    }
    float m = s1 / cnt;
    float v = s2 / cnt - m*m;
    mean[o] = m;
    invstd[o] = rsqrtf(v + 1e-5f);
}

// ---------------- apply BN+LReLU in place on cat slice ----------------
template<int O>
__global__ void apply_kernel(float* __restrict__ catslice,
                             const float* __restrict__ mean, const float* __restrict__ invstd,
                             const float* __restrict__ g, const float* __restrict__ bt){
    int i = blockIdx.x*256 + threadIdx.x;
    int pn = i / O, o = i - pn*O;
    float* p = &catslice[(size_t)pn*512 + o];
    float hn = (*p - mean[o]) * invstd[o] * g[o] + bt[o];
    *p = lrelu(hn);
}

// ---------------- fp32 -> bf16 conversion (4 elems/thread) ----------------
__global__ void tob16_kernel(const float* __restrict__ src, unsigned short* __restrict__ dst, int n4){
    int i = blockIdx.x*256 + threadIdx.x;
    if (i >= n4) return;
    float4 v = *(const float4*)&src[(size_t)i*4];
    ushort4 o;
    o.x = f2b(v.x); o.y = f2b(v.y); o.z = f2b(v.z); o.w = f2b(v.w);
    *(ushort4*)&dst[(size_t)i*4] = o;
}

// ---------------- layer 5 MFMA: catB(32768x512 bf16) @ W5b(1024x512 bf16)^T ----------------
// block 256 = 4 waves (2x2), tile 128x128, BK=64. Fused per-column max/sum/sumsq epilogue.
__global__ void __launch_bounds__(256) l5m_kernel(const unsigned short* __restrict__ Am,
                                                  const unsigned short* __restrict__ Bm,
                                                  float* __restrict__ pmax,
                                                  float* __restrict__ psum,
                                                  float* __restrict__ psq){
    __shared__ __align__(16) unsigned short As[2][128][32];
    __shared__ __align__(16) unsigned short Bs[2][128][32];
    const int tid = threadIdx.x;
    const int r0 = blockIdx.x * 128;
    const int o0 = blockIdx.y * 128;
    const int w = tid >> 6, lane = tid & 63;
    const int quad = lane >> 4, l15 = lane & 15;
    const int mh  = (w & 1) * 64;
    const int nh2 = (w >> 1) * 64;

    f32x4 acc[4][4];
    #pragma unroll
    for (int i=0;i<4;++i)
        #pragma unroll
        for (int j=0;j<4;++j) acc[i][j] = (f32x4){0.f,0.f,0.f,0.f};

    for (int kc = 0; kc < 512; kc += 64){
        __syncthreads();
        #pragma unroll
        for (int t = 0; t < 4; ++t){
            int i = tid + t*256;
            int rr = i >> 3, ch = i & 7;       // 8 chunks of 8 bf16 per row
            *(uint4*)&As[ch>>2][rr][(ch&3)*8] = *(const uint4*)&Am[(size_t)(r0+rr)*512 + kc + ch*8];
            *(uint4*)&Bs[ch>>2][rr][(ch&3)*8] = *(const uint4*)&Bm[(size_t)(o0+rr)*512 + kc + ch*8];
        }
        __syncthreads();
        #pragma unroll
        for (int h = 0; h < 2; ++h){
            short8 af[4], bf[4];
            #pragma unroll
            for (int ms = 0; ms < 4; ++ms) af[ms] = *(const short8*)&As[h][mh + ms*16 + l15][quad*8];
            #pragma unroll
            for (int ns = 0; ns < 4; ++ns) bf[ns] = *(const short8*)&Bs[h][nh2 + ns*16 + l15][quad*8];
            #pragma unroll
            for (int ms = 0; ms < 4; ++ms)
                #pragma unroll
                for (int ns = 0; ns < 4; ++ns)
                    acc[ms][ns] = __builtin_amdgcn_mfma_f32_16x16x32_bf16(af[ms], bf[ns], acc[ms][ns], 0, 0, 0);
        }
    }
    // epilogue: per-column stats over this block's 128 rows (row mapping irrelevant: reduction)
    __syncthreads();
    float* red = (float*)&As[0][0][0];   // 2*128*3 floats, fits in As
    #pragma unroll
    for (int ns = 0; ns < 4; ++ns){
        float mx = -INFINITY, s1 = 0.f, s2 = 0.f;
        #pragma unroll
        for (int ms = 0; ms < 4; ++ms)
            #pragma unroll
            for (int r = 0; r < 4; ++r){
                float v = acc[ms][ns][r];
                mx = fmaxf(mx, v); s1 += v; s2 = fmaf(v, v, s2);
            }
        // reduce over the 4 quads that hold the same column (lanes l15+16q)
        #pragma unroll
        for (int m = 16; m <= 32; m <<= 1){
            mx = fmaxf(mx, __shfl_xor(mx, m));
            s1 += __shfl_xor(s1, m);
            s2 += __shfl_xor(s2, m);
        }
        if (quad == 0){
            int col = nh2 + ns*16 + l15;
            float* p = red + ((size_t)(w & 1) * 128 + col) * 3;
            p[0] = mx; p[1] = s1; p[2] = s2;
        }
    }
    __syncthreads();
    if (tid < 128){
        const float* p0 = red + (size_t)tid*3;
        const float* p1 = red + (size_t)(128 + tid)*3;
        float mx = fmaxf(p0[0], p1[0]);
        float s1 = p0[1] + p1[1];
        float s2 = p0[2] + p1[2];
        size_t pi = (size_t)blockIdx.x*1024 + o0 + tid;
        pmax[pi] = mx; psum[pi] = s1; psq[pi] = s2;
    }
}

__global__ void fin5_kernel(const float* __restrict__ pmax, const float* __restrict__ psum,
                            const float* __restrict__ psq,
                            const float* __restrict__ g, const float* __restrict__ bt,
                            float* __restrict__ out){
    int o = blockIdx.x*256 + threadIdx.x; // 1024 total
    float s1 = 0.f, s2 = 0.f;
    for (int r = 0; r < 256; ++r){
        s1 += psum[(size_t)r*1024 + o];
        s2 += psq [(size_t)r*1024 + o];
    }
    float m  = s1 / 32768.f;
    float v  = s2 / 32768.f - m*m;
    float is = rsqrtf(v + 1e-5f);
    float gg = g[o], bb2 = bt[o];
    for (int b = 0; b < 32; ++b){
        float mx = -INFINITY;
        #pragma unroll
        for (int ns = 0; ns < 8; ++ns) mx = fmaxf(mx, pmax[((size_t)b*8 + ns)*1024 + o]);
        float hn = (mx - m) * is * gg + bb2;
        out[(size_t)b*1024 + o] = lrelu(hn);
    }
}

extern "C" void kernel_launch(void* const* d_in, const int* in_sizes, int n_in,
                              void* d_out, int out_size, void* d_ws, size_t ws_size,
                              hipStream_t stream) {
    (void)in_sizes; (void)n_in; (void)out_size; (void)ws_size;
    const float* x  = (const float*)d_in[0];
    const float* W1 = (const float*)d_in[1];  const float* g1 = (const float*)d_in[2];  const float* b1 = (const float*)d_in[3];
    const float* W2 = (const float*)d_in[4];  const float* g2 = (const float*)d_in[5];  const float* b2 = (const float*)d_in[6];
    const float* W3 = (const float*)d_in[7];  const float* g3 = (const float*)d_in[8];  const float* b3 = (const float*)d_in[9];
    const float* W4 = (const float*)d_in[10]; const float* g4 = (const float*)d_in[11]; const float* b4 = (const float*)d_in[12];
    const float* W5 = (const float*)d_in[13]; const float* g5 = (const float*)d_in[14]; const float* b5 = (const float*)d_in[15];
    float* out = (float*)d_out;

    char* wsp = (char*)d_ws;
    float* cat    = (float*)wsp; wsp += (size_t)PTS*512*4;       // 67.1 MB
    char*  R      = wsp;         wsp += (size_t)8*NN*NN*4;       // 33.55 MB shared region
    int*   idx    = (int*)  wsp; wsp += (size_t)PTS*KNNK*4;      // 2.6 MB
    float* xx     = (float*)wsp; wsp += (size_t)PTS*4;
    float* stats  = (float*)wsp; wsp += (size_t)64*2*256*4;
    float* mean   = (float*)wsp; wsp += 1024*4;
    float* invstd = (float*)wsp; wsp += 1024*4;
    float* pmax   = (float*)wsp; wsp += (size_t)256*1024*4;
    float* psum   = (float*)wsp; wsp += (size_t)256*1024*4;
    float* psq    = (float*)wsp; wsp += (size_t)256*1024*4;
    unsigned short* W5b = (unsigned short*)wsp; wsp += (size_t)1024*512*2;  // 1.05 MB

    // region R aliases (sequentially dead):
    float* Dbuf = (float*)R;                                 // 8-batch distance chunk
    float* G1   = (float*)R;                                 // up to 32768x128 fp32
    float* Gd   = (float*)(R + (size_t)16*1024*1024);        // second half
    unsigned short* catB = (unsigned short*)R;               // 32768x512 bf16 (after layer 4)

    const float cntE = (float)(PTS*KNNK);

    // ---- Layer 1: C=3 -> O=64, cat offset 0 ----
    sq_kernel<<<PTS/256, 256, 0, stream>>>(x, 3, 3, xx);
    for (int bc = 0; bc < 4; ++bc){
        dist_kernel<3><<<dim3(16,16,8), 256, 0, stream>>>(x, 3, xx, Dbuf, bc);
        topk_kernel<<<2048, 256, 0, stream>>>(Dbuf, idx, bc);
    }
    hipMemsetAsync(stats, 0, 64*2*256*4, stream);
    gemmG_kernel<3,64><<<dim3(512,1), 256, 0, stream>>>(x, 3, W1, G1, Gd);
    gather_kernel<64><<<2048, 256, 0, stream>>>(G1, Gd, idx, 0, cat + 0, stats);
    fin_kernel<<<1, 64, 0, stream>>>(stats, 64, cntE, mean, invstd);
    apply_kernel<64><<<PTS*64/256, 256, 0, stream>>>(cat + 0, mean, invstd, g1, b1);

    // ---- Layer 2: C=64 -> O=64, cat offset 64 ----
    sq_kernel<<<PTS/256, 256, 0, stream>>>(cat + 0, 512, 64, xx);
    for (int bc = 0; bc < 4; ++bc){
        dist_kernel<64><<<dim3(16,16,8), 256, 0, stream>>>(cat + 0, 512, xx, Dbuf, bc);
        topk_kernel<<<2048, 256, 0, stream>>>(Dbuf, idx, bc);
    }
    hipMemsetAsync(stats, 0, 64*2*256*4, stream);
    gemmG_kernel<64,64><<<dim3(512,1), 256, 0, stream>>>(cat + 0, 512, W2, G1, Gd);
    gather_kernel<64><<<2048, 256, 0, stream>>>(G1, Gd, idx, 0, cat + 64, stats);
    fin_kernel<<<1, 64, 0, stream>>>(stats, 64, cntE, mean, invstd);
    apply_kernel<64><<<PTS*64/256, 256, 0, stream>>>(cat + 64, mean, invstd, g2, b2);

    // ---- Layer 3: C=64 -> O=128, cat offset 128 ----
    sq_kernel<<<PTS/256, 256, 0, stream>>>(cat + 64, 512, 64, xx);
    for (int bc = 0; bc < 4; ++bc){
        dist_kernel<64><<<dim3(16,16,8), 256, 0, stream>>>(cat + 64, 512, xx, Dbuf, bc);
        topk_kernel<<<2048, 256, 0, stream>>>(Dbuf, idx, bc);
    }
    hipMemsetAsync(stats, 0, 64*2*256*4, stream);
    gemmG_kernel<64,128><<<dim3(512,2), 256, 0, stream>>>(cat + 64, 512, W3, G1, Gd);
    gather_kernel<128><<<2048, 256, 0, stream>>>(G1, Gd, idx, 0, cat + 128, stats);
    fin_kernel<<<1, 128, 0, stream>>>(stats, 128, cntE, mean, invstd);
    apply_kernel<128><<<PTS*128/256, 256, 0, stream>>>(cat + 128, mean, invstd, g3, b3);

    // ---- Layer 4: C=128 -> O=256, cat offset 256 (per-8192-point groups for G1/Gd size) ----
    sq_kernel<<<PTS/256, 256, 0, stream>>>(cat + 128, 512, 128, xx);
    for (int bc = 0; bc < 4; ++bc){
        dist_kernel<128><<<dim3(16,16,8), 256, 0, stream>>>(cat + 128, 512, xx, Dbuf, bc);
        topk_kernel<<<2048, 256, 0, stream>>>(Dbuf, idx, bc);
    }
    hipMemsetAsync(stats, 0, 64*2*256*4, stream);
    for (int bg = 0; bg < 4; ++bg){
        gemmG_kernel<128,256><<<dim3(128,4), 256, 0, stream>>>(cat + 128 + (size_t)bg*8192*512, 512, W4, G1, Gd);
        gather_kernel<256><<<512, 256, 0, stream>>>(G1, Gd, idx, bg*8192, cat + 256, stats);
    }
    fin_kernel<<<1, 256, 0, stream>>>(stats, 256, cntE, mean, invstd);
    apply_kernel<256><<<PTS*256/256, 256, 0, stream>>>(cat + 256, mean, invstd, g4, b4);

    // ---- Layer 5: bf16 MFMA GEMM with fused max/stats ----
    tob16_kernel<<<PTS*512/4/256, 256, 0, stream>>>(cat, catB, PTS*512/4);
    tob16_kernel<<<1024*512/4/256, 256, 0, stream>>>(W5, W5b, 1024*512/4);
    l5m_kernel<<<dim3(256, 8), 256, 0, stream>>>(catB, W5b, pmax, psum, psq);
    fin5_kernel<<<4, 256, 0, stream>>>(pmax, psum, psq, g5, b5, out);
}

// Round 5
// 1499.539 us; speedup vs baseline: 6.7239x; 1.0422x over previous
//
#include <hip/hip_runtime.h>
#include <math.h>

#define BB 32
#define NN 1024
#define KNNK 20
#define PTS (BB*NN)   // 32768

typedef __attribute__((ext_vector_type(8))) short short8;
typedef __attribute__((ext_vector_type(4))) float f32x4;

__device__ __forceinline__ float lrelu(float v){ return v >= 0.f ? v : 0.2f*v; }

__device__ __forceinline__ unsigned short f2b(float x){
    union { float f; unsigned u; } c; c.f = x;
    unsigned r = c.u + 0x7FFFu + ((c.u >> 16) & 1u);
    return (unsigned short)(r >> 16);
}

// ---------------- squared norms per point ----------------
__global__ void sq_kernel(const float* __restrict__ x, int stride, int C, float* __restrict__ xx){
    int pn = blockIdx.x*256 + threadIdx.x;
    if (pn >= PTS) return;
    const float* r = x + (size_t)pn*stride;
    float s = 0.f;
    for (int c = 0; c < C; ++c){ float v = r[c]; s = fmaf(v, v, s); }
    xx[pn] = s;
}

// ---------------- distance GEMM, SYMMETRIC: upper-tri 64x64 tiles, mirrored store ----------------
// grid (136, 1, 8): tile index -> (ti<=tj), batch-in-chunk. Values bit-identical to full version.
template<int C>
__global__ void __launch_bounds__(256) dist_kernel(const float* __restrict__ x, int stride,
                                                   const float* __restrict__ xx,
                                                   float* __restrict__ D, int bc){
    constexpr int KC = (C < 32 ? C : 32);
    __shared__ float As[KC][68];
    __shared__ float Bs[KC][68];
    const int tid = threadIdx.x;
    int t = blockIdx.x, ti = 0;
    while (t >= 16 - ti){ t -= 16 - ti; ++ti; }
    const int tj = ti + t;
    const int i0 = ti * 64;
    const int j0 = tj * 64;
    const int bl = blockIdx.z;            // 0..7 within chunk
    const int b  = bc*8 + bl;
    const float* xb = x + (size_t)b*NN*stride;
    const int rt = tid & 15, ct = tid >> 4;
    float acc[4][4] = {{0.f}};

    for (int kc = 0; kc < C; kc += KC){
        __syncthreads();
        if constexpr (KC % 4 == 0){
            for (int i = tid; i < 64*(KC/4); i += 256){
                int kq = i % (KC/4), rr = i / (KC/4);
                float4 va = *(const float4*)&xb[(size_t)(i0+rr)*stride + kc + kq*4];
                As[kq*4+0][rr]=va.x; As[kq*4+1][rr]=va.y; As[kq*4+2][rr]=va.z; As[kq*4+3][rr]=va.w;
                float4 vb = *(const float4*)&xb[(size_t)(j0+rr)*stride + kc + kq*4];
                Bs[kq*4+0][rr]=vb.x; Bs[kq*4+1][rr]=vb.y; Bs[kq*4+2][rr]=vb.z; Bs[kq*4+3][rr]=vb.w;
            }
        } else {
            for (int i = tid; i < 64*KC; i += 256){
                int k = i % KC, rr = i / KC;
                As[k][rr] = xb[(size_t)(i0+rr)*stride + kc + k];
                Bs[k][rr] = xb[(size_t)(j0+rr)*stride + kc + k];
            }
        }
        __syncthreads();
        #pragma unroll
        for (int k = 0; k < KC; ++k){
            float4 a = *(const float4*)&As[k][rt*4];
            float4 bv= *(const float4*)&Bs[k][ct*4];
            float av[4]={a.x,a.y,a.z,a.w};
            float bw[4]={bv.x,bv.y,bv.z,bv.w};
            #pragma unroll
            for (int i = 0; i < 4; ++i)
                #pragma unroll
                for (int j = 0; j < 4; ++j)
                    acc[i][j] = fmaf(av[i], bw[j], acc[i][j]);
        }
    }
    const float* xxb = xx + b*NN;
    float xi[4], xj[4];
    #pragma unroll
    for (int i=0;i<4;++i) xi[i] = xxb[i0 + rt*4 + i];
    #pragma unroll
    for (int j=0;j<4;++j) xj[j] = xxb[j0 + ct*4 + j];
    // normal tile: row-norm subtracted first (same order as full version)
    #pragma unroll
    for (int i=0;i<4;++i){
        float4 dv;
        dv.x = 2.f*acc[i][0] - xi[i] - xj[0];
        dv.y = 2.f*acc[i][1] - xi[i] - xj[1];
        dv.z = 2.f*acc[i][2] - xi[i] - xj[2];
        dv.w = 2.f*acc[i][3] - xi[i] - xj[3];
        *(float4*)&D[((size_t)bl*NN + i0 + rt*4 + i)*NN + j0 + ct*4] = dv;
    }
    // mirrored tile: for entry (J,I), row-norm is xx[J] -> subtract xj first (bit-identical
    // to what the transposed block computed in the non-symmetric version)
    if (ti != tj){
        #pragma unroll
        for (int j=0;j<4;++j){
            float4 mv;
            mv.x = 2.f*acc[0][j] - xj[j] - xi[0];
            mv.y = 2.f*acc[1][j] - xj[j] - xi[1];
            mv.z = 2.f*acc[2][j] - xj[j] - xi[2];
            mv.w = 2.f*acc[3][j] - xj[j] - xi[3];
            *(float4*)&D[((size_t)bl*NN + j0 + ct*4 + j)*NN + i0 + rt*4] = mv;
        }
    }
}

// ---------------- top-k over D rows: wave per row, register argmax ----------------
__global__ void __launch_bounds__(256) topk_kernel(const float* __restrict__ D,
                                                   int* __restrict__ idxout, int bc){
    const int tid = threadIdx.x;
    const int wv = tid >> 6, lane = tid & 63;
    const int rid = blockIdx.x*4 + wv;       // 0..8191 within chunk
    const float* drow = D + (size_t)rid * NN;
    float v[16];
    #pragma unroll
    for (int i2 = 0; i2 < 16; ++i2) v[i2] = drow[i2*64 + lane];
    int* orow = idxout + ((size_t)bc*8192 + rid) * KNNK;
    for (int t = 0; t < KNNK; ++t){
        float bv = v[0]; int bs = 0;
        #pragma unroll
        for (int i2 = 1; i2 < 16; ++i2){ if (v[i2] > bv){ bv = v[i2]; bs = i2; } }
        int bj = bs*64 + lane;
        #pragma unroll
        for (int m = 32; m; m >>= 1){
            float ov = __shfl_xor(bv, m);
            int   oj = __shfl_xor(bj, m);
            if (ov > bv || (ov == bv && oj < bj)){ bv = ov; bj = oj; }
        }
        int clr = ((bj & 63) == lane) ? (bj >> 6) : -1;
        #pragma unroll
        for (int i2 = 0; i2 < 16; ++i2) if (i2 == clr) v[i2] = -INFINITY;
        if (lane == 0) orow[t] = bj;
    }
}

// ---------------- G GEMMs: G1 = X @ W[:, :C]^T ; Gd = X @ (W[:,C:]-W[:, :C])^T ----------------
template<int C, int O>
__global__ void __launch_bounds__(256) gemmG_kernel(const float* __restrict__ x, int stride,
                                                    const float* __restrict__ W,
                                                    float* __restrict__ G1, float* __restrict__ Gd){
    constexpr int KC = (C < 32 ? C : 32);
    __shared__ float Xl [KC][68];
    __shared__ float W1l[KC][68];
    __shared__ float W2l[KC][68];
    const int tid = threadIdx.x;
    const int r0 = blockIdx.x * 64;
    const int o0 = blockIdx.y * 64;
    const int rt = tid & 15, ct = tid >> 4;

    float a1[4][4] = {{0.f}}, a2[4][4] = {{0.f}};
    for (int kc = 0; kc < C; kc += KC){
        __syncthreads();
        for (int i = tid; i < KC*64; i += 256){
            int k = i % KC, rr = i / KC;
            Xl [k][rr] = x[(size_t)(r0+rr)*stride + kc + k];
            W1l[k][rr] = W[(size_t)(o0+rr)*(2*C) + kc + k];
            W2l[k][rr] = W[(size_t)(o0+rr)*(2*C) + C + kc + k];
        }
        __syncthreads();
        #pragma unroll
        for (int k = 0; k < KC; ++k){
            float4 xa = *(const float4*)&Xl [k][rt*4];
            float4 w1 = *(const float4*)&W1l[k][ct*4];
            float4 w2 = *(const float4*)&W2l[k][ct*4];
            float xv[4] = {xa.x, xa.y, xa.z, xa.w};
            #pragma unroll
            for (int i = 0; i < 4; ++i){
                a1[i][0] = fmaf(xv[i], w1.x, a1[i][0]);
                a1[i][1] = fmaf(xv[i], w1.y, a1[i][1]);
                a1[i][2] = fmaf(xv[i], w1.z, a1[i][2]);
                a1[i][3] = fmaf(xv[i], w1.w, a1[i][3]);
                a2[i][0] = fmaf(xv[i], w2.x, a2[i][0]);
                a2[i][1] = fmaf(xv[i], w2.y, a2[i][1]);
                a2[i][2] = fmaf(xv[i], w2.z, a2[i][2]);
                a2[i][3] = fmaf(xv[i], w2.w, a2[i][3]);
            }
        }
    }
    #pragma unroll
    for (int i = 0; i < 4; ++i){
        size_t row = (size_t)(r0 + rt*4 + i);
        float4 g1v = make_float4(a1[i][0], a1[i][1], a1[i][2], a1[i][3]);
        float4 gdv = make_float4(a2[i][0]-a1[i][0], a2[i][1]-a1[i][1],
                                 a2[i][2]-a1[i][2], a2[i][3]-a1[i][3]);
        *(float4*)&G1[row*O + o0 + ct*4] = g1v;
        *(float4*)&Gd[row*O + o0 + ct*4] = gdv;
    }
}

// ---------------- gather: per (point,o) max/sum/sumsq over k via G1 rows ----------------
template<int O>
__global__ void __launch_bounds__(256) gather_kernel(const float* __restrict__ G1,
                                                     const float* __restrict__ Gd,
                                                     const int* __restrict__ idxg, int bgbase,
                                                     float* __restrict__ catslice,
                                                     float* __restrict__ stats){
    constexpr int PP = 256 / O;
    constexpr int NP = 16;
    __shared__ int nbs[NP][KNNK];
    const int tid = threadIdx.x;
    const int p0 = blockIdx.x * NP;
    for (int i = tid; i < NP*KNNK; i += 256){
        int pp = i / KNNK, kk = i - pp*KNNK;
        int pl = p0 + pp;
        int nb = idxg[(size_t)(bgbase + pl)*KNNK + kk];
        nbs[pp][kk] = ((pl >> 10) << 10) + nb;
    }
    __syncthreads();
    const int o  = tid % O;
    const int pq = tid / O;
    float s1 = 0.f, s2 = 0.f;
    for (int pp = pq; pp < NP; pp += PP){
        int pl = p0 + pp;
        float d = Gd[(size_t)pl*O + o];
        float mx = -INFINITY, ls = 0.f, lq = 0.f;
        #pragma unroll
        for (int kk = 0; kk < KNNK; ++kk){
            float g = G1[(size_t)nbs[pp][kk]*O + o];
            mx = fmaxf(mx, g);
            ls += g;
            lq = fmaf(g, g, lq);
        }
        s1 += ls + 20.f*d;
        s2 += lq + 2.f*d*ls + 20.f*d*d;
        catslice[(size_t)(bgbase + pl)*512 + o] = mx + d;
    }
    int rep = blockIdx.x & 63;
    atomicAdd(&stats[rep*2*O + o],     s1);
    atomicAdd(&stats[rep*2*O + O + o], s2);
}

// ---------------- finalize BN stats ----------------
__global__ void fin_kernel(const float* __restrict__ stats, int O, float cnt,
                           float* __restrict__ mean, float* __restrict__ invstd){
    int o = threadIdx.x;
    if (o >= O) return;
    float s1 = 0.f, s2 = 0.f;
    for (int r = 0; r < 64; ++r){
        s1 += stats[r*2*O + o];
        s2 += stats[r*2*O + O + o];
    }
    float m = s1 / cnt;
    float v = s2 / cnt - m*m;
    mean[o] = m;
    invstd[o] = rsqrtf(v + 1e-5f);
}

// ---------------- apply BN+LReLU in place on cat slice ----------------
template<int O>
__global__ void apply_kernel(float* __restrict__ catslice,
                             const float* __restrict__ mean, const float* __restrict__ invstd,
                             const float* __restrict__ g, const float* __restrict__ bt){
    int i = blockIdx.x*256 + threadIdx.x;
    int pn = i / O, o = i - pn*O;
    float* p = &catslice[(size_t)pn*512 + o];
    float hn = (*p - mean[o]) * invstd[o] * g[o] + bt[o];
    *p = lrelu(hn);
}

// ---------------- fp32 -> bf16 conversion (4 elems/thread) ----------------
__global__ void tob16_kernel(const float* __restrict__ src, unsigned short* __restrict__ dst, int n4){
    int i = blockIdx.x*256 + threadIdx.x;
    if (i >= n4) return;
    float4 v = *(const float4*)&src[(size_t)i*4];
    ushort4 o;
    o.x = f2b(v.x); o.y = f2b(v.y); o.z = f2b(v.z); o.w = f2b(v.w);
    *(ushort4*)&dst[(size_t)i*4] = o;
}

// ---------------- layer 5 MFMA: catB(32768x512 bf16) @ W5b(1024x512 bf16)^T ----------------
// block 256 = 4 waves (2x2), tile 128x128, BK=64. XOR-swizzled LDS (kills 8-way conflicts).
__global__ void __launch_bounds__(256) l5m_kernel(const unsigned short* __restrict__ Am,
                                                  const unsigned short* __restrict__ Bm,
                                                  float* __restrict__ pmax,
                                                  float* __restrict__ psum,
                                                  float* __restrict__ psq){
    __shared__ __align__(16) unsigned short As[2][128][32];
    __shared__ __align__(16) unsigned short Bs[2][128][32];
    const int tid = threadIdx.x;
    const int r0 = blockIdx.x * 128;
    const int o0 = blockIdx.y * 128;
    const int w = tid >> 6, lane = tid & 63;
    const int quad = lane >> 4, l15 = lane & 15;
    const int mh  = (w & 1) * 64;
    const int nh2 = (w >> 1) * 64;
    const int sw  = (quad ^ (l15 & 3)) * 8;   // swizzled 16-B chunk slot for reads

    f32x4 acc[4][4];
    #pragma unroll
    for (int i=0;i<4;++i)
        #pragma unroll
        for (int j=0;j<4;++j) acc[i][j] = (f32x4){0.f,0.f,0.f,0.f};

    for (int kc = 0; kc < 512; kc += 64){
        __syncthreads();
        #pragma unroll
        for (int t = 0; t < 4; ++t){
            int i = tid + t*256;
            int rr = i >> 3, ch = i & 7;       // 8 chunks of 8 bf16 per row
            int cs = ((ch & 3) ^ (rr & 3)) * 8;  // swizzled store slot
            *(uint4*)&As[ch>>2][rr][cs] = *(const uint4*)&Am[(size_t)(r0+rr)*512 + kc + ch*8];
            *(uint4*)&Bs[ch>>2][rr][cs] = *(const uint4*)&Bm[(size_t)(o0+rr)*512 + kc + ch*8];
        }
        __syncthreads();
        #pragma unroll
        for (int h = 0; h < 2; ++h){
            short8 af[4], bf[4];
            #pragma unroll
            for (int ms = 0; ms < 4; ++ms) af[ms] = *(const short8*)&As[h][mh + ms*16 + l15][sw];
            #pragma unroll
            for (int ns = 0; ns < 4; ++ns) bf[ns] = *(const short8*)&Bs[h][nh2 + ns*16 + l15][sw];
            #pragma unroll
            for (int ms = 0; ms < 4; ++ms)
                #pragma unroll
                for (int ns = 0; ns < 4; ++ns)
                    acc[ms][ns] = __builtin_amdgcn_mfma_f32_16x16x32_bf16(af[ms], bf[ns], acc[ms][ns], 0, 0, 0);
        }
    }
    // epilogue: per-column stats over this block's 128 rows (row mapping irrelevant: reduction)
    __syncthreads();
    float* red = (float*)&As[0][0][0];   // 2*128*3 floats, fits in As
    #pragma unroll
    for (int ns = 0; ns < 4; ++ns){
        float mx = -INFINITY, s1 = 0.f, s2 = 0.f;
        #pragma unroll
        for (int ms = 0; ms < 4; ++ms)
            #pragma unroll
            for (int r = 0; r < 4; ++r){
                float v = acc[ms][ns][r];
                mx = fmaxf(mx, v); s1 += v; s2 = fmaf(v, v, s2);
            }
        #pragma unroll
        for (int m = 16; m <= 32; m <<= 1){
            mx = fmaxf(mx, __shfl_xor(mx, m));
            s1 += __shfl_xor(s1, m);
            s2 += __shfl_xor(s2, m);
        }
        if (quad == 0){
            int col = nh2 + ns*16 + l15;
            float* p = red + ((size_t)(w & 1) * 128 + col) * 3;
            p[0] = mx; p[1] = s1; p[2] = s2;
        }
    }
    __syncthreads();
    if (tid < 128){
        const float* p0 = red + (size_t)tid*3;
        const float* p1 = red + (size_t)(128 + tid)*3;
        float mx = fmaxf(p0[0], p1[0]);
        float s1 = p0[1] + p1[1];
        float s2 = p0[2] + p1[2];
        size_t pi = (size_t)blockIdx.x*1024 + o0 + tid;
        pmax[pi] = mx; psum[pi] = s1; psq[pi] = s2;
    }
}

__global__ void fin5_kernel(const float* __restrict__ pmax, const float* __restrict__ psum,
                            const float* __restrict__ psq,
                            const float* __restrict__ g, const float* __restrict__ bt,
                            float* __restrict__ out){
    int o = blockIdx.x*256 + threadIdx.x; // 1024 total
    float s1 = 0.f, s2 = 0.f;
    for (int r = 0; r < 256; ++r){
        s1 += psum[(size_t)r*1024 + o];
        s2 += psq [(size_t)r*1024 + o];
    }
    float m  = s1 / 32768.f;
    float v  = s2 / 32768.f - m*m;
    float is = rsqrtf(v + 1e-5f);
    float gg = g[o], bb2 = bt[o];
    for (int b = 0; b < 32; ++b){
        float mx = -INFINITY;
        #pragma unroll
        for (int ns = 0; ns < 8; ++ns) mx = fmaxf(mx, pmax[((size_t)b*8 + ns)*1024 + o]);
        float hn = (mx - m) * is * gg + bb2;
        out[(size_t)b*1024 + o] = lrelu(hn);
    }
}

extern "C" void kernel_launch(void* const* d_in, const int* in_sizes, int n_in,
                              void* d_out, int out_size, void* d_ws, size_t ws_size,
                              hipStream_t stream) {
    (void)in_sizes; (void)n_in; (void)out_size; (void)ws_size;
    const float* x  = (const float*)d_in[0];
    const float* W1 = (const float*)d_in[1];  const float* g1 = (const float*)d_in[2];  const float* b1 = (const float*)d_in[3];
    const float* W2 = (const float*)d_in[4];  const float* g2 = (const float*)d_in[5];  const float* b2 = (const float*)d_in[6];
    const float* W3 = (const float*)d_in[7];  const float* g3 = (const float*)d_in[8];  const float* b3 = (const float*)d_in[9];
    const float* W4 = (const float*)d_in[10]; const float* g4 = (const float*)d_in[11]; const float* b4 = (const float*)d_in[12];
    const float* W5 = (const float*)d_in[13]; const float* g5 = (const float*)d_in[14]; const float* b5 = (const float*)d_in[15];
    float* out = (float*)d_out;

    char* wsp = (char*)d_ws;
    float* cat    = (float*)wsp; wsp += (size_t)PTS*512*4;       // 67.1 MB
    char*  R      = wsp;         wsp += (size_t)8*NN*NN*4;       // 33.55 MB shared region
    int*   idx    = (int*)  wsp; wsp += (size_t)PTS*KNNK*4;      // 2.6 MB
    float* xx     = (float*)wsp; wsp += (size_t)PTS*4;
    float* stats  = (float*)wsp; wsp += (size_t)64*2*256*4;
    float* mean   = (float*)wsp; wsp += 1024*4;
    float* invstd = (float*)wsp; wsp += 1024*4;
    float* pmax   = (float*)wsp; wsp += (size_t)256*1024*4;
    float* psum   = (float*)wsp; wsp += (size_t)256*1024*4;
    float* psq    = (float*)wsp; wsp += (size_t)256*1024*4;
    unsigned short* W5b = (unsigned short*)wsp; wsp += (size_t)1024*512*2;  // 1.05 MB

    // region R aliases (sequentially dead):
    float* Dbuf = (float*)R;                                 // 8-batch distance chunk
    float* G1   = (float*)R;                                 // up to 32768x128 fp32
    float* Gd   = (float*)(R + (size_t)16*1024*1024);        // second half
    unsigned short* catB = (unsigned short*)R;               // 32768x512 bf16 (after layer 4)

    const float cntE = (float)(PTS*KNNK);

    // ---- Layer 1: C=3 -> O=64, cat offset 0 ----
    sq_kernel<<<PTS/256, 256, 0, stream>>>(x, 3, 3, xx);
    for (int bc = 0; bc < 4; ++bc){
        dist_kernel<3><<<dim3(136,1,8), 256, 0, stream>>>(x, 3, xx, Dbuf, bc);
        topk_kernel<<<2048, 256, 0, stream>>>(Dbuf, idx, bc);
    }
    hipMemsetAsync(stats, 0, 64*2*256*4, stream);
    gemmG_kernel<3,64><<<dim3(512,1), 256, 0, stream>>>(x, 3, W1, G1, Gd);
    gather_kernel<64><<<2048, 256, 0, stream>>>(G1, Gd, idx, 0, cat + 0, stats);
    fin_kernel<<<1, 64, 0, stream>>>(stats, 64, cntE, mean, invstd);
    apply_kernel<64><<<PTS*64/256, 256, 0, stream>>>(cat + 0, mean, invstd, g1, b1);

    // ---- Layer 2: C=64 -> O=64, cat offset 64 ----
    sq_kernel<<<PTS/256, 256, 0, stream>>>(cat + 0, 512, 64, xx);
    for (int bc = 0; bc < 4; ++bc){
        dist_kernel<64><<<dim3(136,1,8), 256, 0, stream>>>(cat + 0, 512, xx, Dbuf, bc);
        topk_kernel<<<2048, 256, 0, stream>>>(Dbuf, idx, bc);
    }
    hipMemsetAsync(stats, 0, 64*2*256*4, stream);
    gemmG_kernel<64,64><<<dim3(512,1), 256, 0, stream>>>(cat + 0, 512, W2, G1, Gd);
    gather_kernel<64><<<2048, 256, 0, stream>>>(G1, Gd, idx, 0, cat + 64, stats);
    fin_kernel<<<1, 64, 0, stream>>>(stats, 64, cntE, mean, invstd);
    apply_kernel<64><<<PTS*64/256, 256, 0, stream>>>(cat + 64, mean, invstd, g2, b2);

    // ---- Layer 3: C=64 -> O=128, cat offset 128 ----
    sq_kernel<<<PTS/256, 256, 0, stream>>>(cat + 64, 512, 64, xx);
    for (int bc = 0; bc < 4; ++bc){
        dist_kernel<64><<<dim3(136,1,8), 256, 0, stream>>>(cat + 64, 512, xx, Dbuf, bc);
        topk_kernel<<<2048, 256, 0, stream>>>(Dbuf, idx, bc);
    }
    hipMemsetAsync(stats, 0, 64*2*256*4, stream);
    gemmG_kernel<64,128><<<dim3(512,2), 256, 0, stream>>>(cat + 64, 512, W3, G1, Gd);
    gather_kernel<128><<<2048, 256, 0, stream>>>(G1, Gd, idx, 0, cat + 128, stats);
    fin_kernel<<<1, 128, 0, stream>>>(stats, 128, cntE, mean, invstd);
    apply_kernel<128><<<PTS*128/256, 256, 0, stream>>>(cat + 128, mean, invstd, g3, b3);

    // ---- Layer 4: C=128 -> O=256, cat offset 256 (per-8192-point groups for G1/Gd size) ----
    sq_kernel<<<PTS/256, 256, 0, stream>>>(cat + 128, 512, 128, xx);
    for (int bc = 0; bc < 4; ++bc){
        dist_kernel<128><<<dim3(136,1,8), 256, 0, stream>>>(cat + 128, 512, xx, Dbuf, bc);
        topk_kernel<<<2048, 256, 0, stream>>>(Dbuf, idx, bc);
    }
    hipMemsetAsync(stats, 0, 64*2*256*4, stream);
    for (int bg = 0; bg < 4; ++bg){
        gemmG_kernel<128,256><<<dim3(128,4), 256, 0, stream>>>(cat + 128 + (size_t)bg*8192*512, 512, W4, G1, Gd);
        gather_kernel<256><<<512, 256, 0, stream>>>(G1, Gd, idx, bg*8192, cat + 256, stats);
    }
    fin_kernel<<<1, 256, 0, stream>>>(stats, 256, cntE, mean, invstd);
    apply_kernel<256><<<PTS*256/256, 256, 0, stream>>>(cat + 256, mean, invstd, g4, b4);

    // ---- Layer 5: bf16 MFMA GEMM with fused max/stats ----
    tob16_kernel<<<PTS*512/4/256, 256, 0, stream>>>(cat, catB, PTS*512/4);
    tob16_kernel<<<1024*512/4/256, 256, 0, stream>>>(W5, W5b, 1024*512/4);
    l5m_kernel<<<dim3(256, 8), 256, 0, stream>>>(catB, W5b, pmax, psum, psq);
    fin5_kernel<<<4, 256, 0, stream>>>(pmax, psum, psq, g5, b5, out);
}

// Round 6
// 1253.340 us; speedup vs baseline: 8.0447x; 1.1964x over previous
//
#include <hip/hip_runtime.h>
#include <math.h>

#define BB 32
#define NN 1024
#define KNNK 20
#define PTS (BB*NN)   // 32768

typedef __attribute__((ext_vector_type(8)))  short short8;
typedef __attribute__((ext_vector_type(4)))  float f32x4;
typedef __attribute__((ext_vector_type(16))) float f32x16;

__device__ __forceinline__ float lrelu(float v){ return v >= 0.f ? v : 0.2f*v; }

__device__ __forceinline__ unsigned short f2b(float x){
    union { float f; unsigned u; } c; c.f = x;
    unsigned r = c.u + 0x7FFFu + ((c.u >> 16) & 1u);
    return (unsigned short)(r >> 16);
}

// ---------------- squared norms per point ----------------
__global__ void sq_kernel(const float* __restrict__ x, int stride, int C, float* __restrict__ xx){
    int pn = blockIdx.x*256 + threadIdx.x;
    if (pn >= PTS) return;
    const float* r = x + (size_t)pn*stride;
    float s = 0.f;
    for (int c = 0; c < C; ++c){ float v = r[c]; s = fmaf(v, v, s); }
    xx[pn] = s;
}

// ---------------- distance GEMM, SYMMETRIC: upper-tri 128x128 tiles, 8x8/thread ----------------
// grid (36, 1, CB). Values bit-identical to previous rounds (same FMA k-order, same sub order).
template<int C>
__global__ void __launch_bounds__(256) dist_kernel(const float* __restrict__ x, int stride,
                                                   const float* __restrict__ xx,
                                                   float* __restrict__ D, int b0){
    constexpr int KC = (C < 32 ? C : 32);
    __shared__ float As[KC][132];
    __shared__ float Bs[KC][132];
    const int tid = threadIdx.x;
    int t = blockIdx.x, ti = 0;
    while (t >= 8 - ti){ t -= 8 - ti; ++ti; }
    const int tj = ti + t;
    const int i0 = ti*128, j0 = tj*128;
    const int bl = blockIdx.z;
    const int b  = b0 + bl;
    const float* xb = x + (size_t)b*NN*stride;
    const int rt = tid >> 4, ct = tid & 15;   // ct fastest -> coalesced normal stores
    float acc[8][8] = {{0.f}};

    for (int kc = 0; kc < C; kc += KC){
        __syncthreads();
        if constexpr (KC % 4 == 0){
            for (int i = tid; i < 128*(KC/4); i += 256){
                int kq = i % (KC/4), rr = i / (KC/4);
                float4 va = *(const float4*)&xb[(size_t)(i0+rr)*stride + kc + kq*4];
                As[kq*4+0][rr]=va.x; As[kq*4+1][rr]=va.y; As[kq*4+2][rr]=va.z; As[kq*4+3][rr]=va.w;
                float4 vb = *(const float4*)&xb[(size_t)(j0+rr)*stride + kc + kq*4];
                Bs[kq*4+0][rr]=vb.x; Bs[kq*4+1][rr]=vb.y; Bs[kq*4+2][rr]=vb.z; Bs[kq*4+3][rr]=vb.w;
            }
        } else {
            for (int i = tid; i < 128*KC; i += 256){
                int k = i % KC, rr = i / KC;
                As[k][rr] = xb[(size_t)(i0+rr)*stride + kc + k];
                Bs[k][rr] = xb[(size_t)(j0+rr)*stride + kc + k];
            }
        }
        __syncthreads();
        #pragma unroll
        for (int k = 0; k < KC; ++k){
            float4 a0 = *(const float4*)&As[k][rt*8];
            float4 a1 = *(const float4*)&As[k][rt*8+4];
            float4 b0v= *(const float4*)&Bs[k][ct*8];
            float4 b1v= *(const float4*)&Bs[k][ct*8+4];
            float av[8]={a0.x,a0.y,a0.z,a0.w,a1.x,a1.y,a1.z,a1.w};
            float bw[8]={b0v.x,b0v.y,b0v.z,b0v.w,b1v.x,b1v.y,b1v.z,b1v.w};
            #pragma unroll
            for (int i = 0; i < 8; ++i)
                #pragma unroll
                for (int j = 0; j < 8; ++j)
                    acc[i][j] = fmaf(av[i], bw[j], acc[i][j]);
        }
    }
    const float* xxb = xx + b*NN;
    float xi[8], xj[8];
    #pragma unroll
    for (int i=0;i<8;++i) xi[i] = xxb[i0 + rt*8 + i];
    #pragma unroll
    for (int j=0;j<8;++j) xj[j] = xxb[j0 + ct*8 + j];
    // normal tile: row-norm subtracted first (order identical to prior rounds)
    #pragma unroll
    for (int i=0;i<8;++i){
        float4 d0, d1;
        d0.x = 2.f*acc[i][0] - xi[i] - xj[0];
        d0.y = 2.f*acc[i][1] - xi[i] - xj[1];
        d0.z = 2.f*acc[i][2] - xi[i] - xj[2];
        d0.w = 2.f*acc[i][3] - xi[i] - xj[3];
        d1.x = 2.f*acc[i][4] - xi[i] - xj[4];
        d1.y = 2.f*acc[i][5] - xi[i] - xj[5];
        d1.z = 2.f*acc[i][6] - xi[i] - xj[6];
        d1.w = 2.f*acc[i][7] - xi[i] - xj[7];
        float* drow = &D[((size_t)bl*NN + i0 + rt*8 + i)*NN + j0 + ct*8];
        *(float4*)drow = d0;
        *(float4*)(drow+4) = d1;
    }
    // mirrored tile: row-norm of the mirrored row (xx[col of normal]) subtracted first
    if (ti != tj){
        #pragma unroll
        for (int j=0;j<8;++j){
            float4 m0, m1;
            m0.x = 2.f*acc[0][j] - xj[j] - xi[0];
            m0.y = 2.f*acc[1][j] - xj[j] - xi[1];
            m0.z = 2.f*acc[2][j] - xj[j] - xi[2];
            m0.w = 2.f*acc[3][j] - xj[j] - xi[3];
            m1.x = 2.f*acc[4][j] - xj[j] - xi[4];
            m1.y = 2.f*acc[5][j] - xj[j] - xi[5];
            m1.z = 2.f*acc[6][j] - xj[j] - xi[6];
            m1.w = 2.f*acc[7][j] - xj[j] - xi[7];
            float* mrow = &D[((size_t)bl*NN + j0 + ct*8 + j)*NN + i0 + rt*8];
            *(float4*)mrow = m0;
            *(float4*)(mrow+4) = m1;
        }
    }
}

// ---------------- top-k over D rows: wave per row, register argmax ----------------
__global__ void __launch_bounds__(256) topk_kernel(const float* __restrict__ D,
                                                   int* __restrict__ idxout, int baseRow){
    const int tid = threadIdx.x;
    const int wv = tid >> 6, lane = tid & 63;
    const int rid = blockIdx.x*4 + wv;
    const float* drow = D + (size_t)rid * NN;
    float v[16];
    #pragma unroll
    for (int i2 = 0; i2 < 16; ++i2) v[i2] = drow[i2*64 + lane];
    int* orow = idxout + ((size_t)baseRow + rid) * KNNK;
    for (int t = 0; t < KNNK; ++t){
        float bv = v[0]; int bs = 0;
        #pragma unroll
        for (int i2 = 1; i2 < 16; ++i2){ if (v[i2] > bv){ bv = v[i2]; bs = i2; } }
        int bj = bs*64 + lane;
        #pragma unroll
        for (int m = 32; m; m >>= 1){
            float ov = __shfl_xor(bv, m);
            int   oj = __shfl_xor(bj, m);
            if (ov > bv || (ov == bv && oj < bj)){ bv = ov; bj = oj; }
        }
        int clr = ((bj & 63) == lane) ? (bj >> 6) : -1;
        #pragma unroll
        for (int i2 = 0; i2 < 16; ++i2) if (i2 == clr) v[i2] = -INFINITY;
        if (lane == 0) orow[t] = bj;
    }
}

// ---------------- G GEMMs: G1 = X @ W[:, :C]^T ; Gd = X @ (W[:,C:]-W[:, :C])^T ----------------
template<int C, int O>
__global__ void __launch_bounds__(256) gemmG_kernel(const float* __restrict__ x, int stride,
                                                    const float* __restrict__ W,
                                                    float* __restrict__ G1, float* __restrict__ Gd){
    constexpr int KC = (C < 32 ? C : 32);
    __shared__ float Xl [KC][68];
    __shared__ float W1l[KC][68];
    __shared__ float W2l[KC][68];
    const int tid = threadIdx.x;
    const int r0 = blockIdx.x * 64;
    const int o0 = blockIdx.y * 64;
    const int rt = tid & 15, ct = tid >> 4;

    float a1[4][4] = {{0.f}}, a2[4][4] = {{0.f}};
    for (int kc = 0; kc < C; kc += KC){
        __syncthreads();
        for (int i = tid; i < KC*64; i += 256){
            int k = i % KC, rr = i / KC;
            Xl [k][rr] = x[(size_t)(r0+rr)*stride + kc + k];
            W1l[k][rr] = W[(size_t)(o0+rr)*(2*C) + kc + k];
            W2l[k][rr] = W[(size_t)(o0+rr)*(2*C) + C + kc + k];
        }
        __syncthreads();
        #pragma unroll
        for (int k = 0; k < KC; ++k){
            float4 xa = *(const float4*)&Xl [k][rt*4];
            float4 w1 = *(const float4*)&W1l[k][ct*4];
            float4 w2 = *(const float4*)&W2l[k][ct*4];
            float xv[4] = {xa.x, xa.y, xa.z, xa.w};
            #pragma unroll
            for (int i = 0; i < 4; ++i){
                a1[i][0] = fmaf(xv[i], w1.x, a1[i][0]);
                a1[i][1] = fmaf(xv[i], w1.y, a1[i][1]);
                a1[i][2] = fmaf(xv[i], w1.z, a1[i][2]);
                a1[i][3] = fmaf(xv[i], w1.w, a1[i][3]);
                a2[i][0] = fmaf(xv[i], w2.x, a2[i][0]);
                a2[i][1] = fmaf(xv[i], w2.y, a2[i][1]);
                a2[i][2] = fmaf(xv[i], w2.z, a2[i][2]);
                a2[i][3] = fmaf(xv[i], w2.w, a2[i][3]);
            }
        }
    }
    #pragma unroll
    for (int i = 0; i < 4; ++i){
        size_t row = (size_t)(r0 + rt*4 + i);
        float4 g1v = make_float4(a1[i][0], a1[i][1], a1[i][2], a1[i][3]);
        float4 gdv = make_float4(a2[i][0]-a1[i][0], a2[i][1]-a1[i][1],
                                 a2[i][2]-a1[i][2], a2[i][3]-a1[i][3]);
        *(float4*)&G1[row*O + o0 + ct*4] = g1v;
        *(float4*)&Gd[row*O + o0 + ct*4] = gdv;
    }
}

// ---------------- gather: per (point,o) max/sum/sumsq over k via G1 rows ----------------
template<int O>
__global__ void __launch_bounds__(256) gather_kernel(const float* __restrict__ G1,
                                                     const float* __restrict__ Gd,
                                                     const int* __restrict__ idxg, int bgbase,
                                                     float* __restrict__ catslice,
                                                     float* __restrict__ stats){
    constexpr int PP = 256 / O;
    constexpr int NP = 16;
    __shared__ int nbs[NP][KNNK];
    const int tid = threadIdx.x;
    const int p0 = blockIdx.x * NP;
    for (int i = tid; i < NP*KNNK; i += 256){
        int pp = i / KNNK, kk = i - pp*KNNK;
        int pl = p0 + pp;
        int nb = idxg[(size_t)(bgbase + pl)*KNNK + kk];
        nbs[pp][kk] = ((pl >> 10) << 10) + nb;
    }
    __syncthreads();
    const int o  = tid % O;
    const int pq = tid / O;
    float s1 = 0.f, s2 = 0.f;
    for (int pp = pq; pp < NP; pp += PP){
        int pl = p0 + pp;
        float d = Gd[(size_t)pl*O + o];
        float mx = -INFINITY, ls = 0.f, lq = 0.f;
        #pragma unroll
        for (int kk = 0; kk < KNNK; ++kk){
            float g = G1[(size_t)nbs[pp][kk]*O + o];
            mx = fmaxf(mx, g);
            ls += g;
            lq = fmaf(g, g, lq);
        }
        s1 += ls + 20.f*d;
        s2 += lq + 2.f*d*ls + 20.f*d*d;
        catslice[(size_t)(bgbase + pl)*512 + o] = mx + d;
    }
    int rep = blockIdx.x & 63;
    atomicAdd(&stats[rep*2*O + o],     s1);
    atomicAdd(&stats[rep*2*O + O + o], s2);
}

// ---------------- finalize BN stats ----------------
__global__ void fin_kernel(const float* __restrict__ stats, int O, float cnt,
                           float* __restrict__ mean, float* __restrict__ invstd){
    int o = threadIdx.x;
    if (o >= O) return;
    float s1 = 0.f, s2 = 0.f;
    for (int r = 0; r < 64; ++r){
        s1 += stats[r*2*O + o];
        s2 += stats[r*2*O + O + o];
    }
    float m = s1 / cnt;
    float v = s2 / cnt - m*m;
    mean[o] = m;
    invstd[o] = rsqrtf(v + 1e-5f);
}

// ---------------- apply BN+LReLU in place on cat slice ----------------
template<int O>
__global__ void apply_kernel(float* __restrict__ catslice,
                             const float* __restrict__ mean, const float* __restrict__ invstd,
                             const float* __restrict__ g, const float* __restrict__ bt){
    int i = blockIdx.x*256 + threadIdx.x;
    int pn = i / O, o = i - pn*O;
    float* p = &catslice[(size_t)pn*512 + o];
    float hn = (*p - mean[o]) * invstd[o] * g[o] + bt[o];
    *p = lrelu(hn);
}

// ---------------- fp32 -> bf16 conversion (4 elems/thread) ----------------
__global__ void tob16_kernel(const float* __restrict__ src, unsigned short* __restrict__ dst, int n4){
    int i = blockIdx.x*256 + threadIdx.x;
    if (i >= n4) return;
    float4 v = *(const float4*)&src[(size_t)i*4];
    ushort4 o;
    o.x = f2b(v.x); o.y = f2b(v.y); o.z = f2b(v.z); o.w = f2b(v.w);
    *(ushort4*)&dst[(size_t)i*4] = o;
}

// ---------------- layer 5 MFMA v2: 32x32x16 frags, 64x64/wave, 128x128/block ----------------
__global__ void __launch_bounds__(256) l5m_kernel(const unsigned short* __restrict__ Am,
                                                  const unsigned short* __restrict__ Bm,
                                                  float* __restrict__ pmax,
                                                  float* __restrict__ psum,
                                                  float* __restrict__ psq){
    __shared__ __align__(16) unsigned short As[128][64];
    __shared__ __align__(16) unsigned short Bs[128][64];
    const int tid = threadIdx.x;
    const int r0 = blockIdx.x * 128;
    const int o0 = blockIdx.y * 128;
    const int w = tid >> 6, lane = tid & 63;
    const int m32 = lane & 31, kh = lane >> 5;
    const int wm = (w & 1) * 64;
    const int wn = (w >> 1) * 64;

    f32x16 acc[2][2];
    #pragma unroll
    for (int i=0;i<2;++i)
        #pragma unroll
        for (int j=0;j<2;++j)
            #pragma unroll
            for (int r=0;r<16;++r) acc[i][j][r] = 0.f;

    for (int kc = 0; kc < 512; kc += 64){
        __syncthreads();
        #pragma unroll
        for (int t = 0; t < 4; ++t){
            int i = tid + t*256;
            int rr = i >> 3, ch = i & 7;
            int sl = ch ^ (rr & 7);
            *(uint4*)&As[rr][sl*8] = *(const uint4*)&Am[(size_t)(r0+rr)*512 + kc + ch*8];
            *(uint4*)&Bs[rr][sl*8] = *(const uint4*)&Bm[(size_t)(o0+rr)*512 + kc + ch*8];
        }
        __syncthreads();
        #pragma unroll
        for (int q = 0; q < 4; ++q){
            int lk = q*2 + kh;
            short8 a[2], bfr[2];
            #pragma unroll
            for (int mb = 0; mb < 2; ++mb){
                int rA = wm + mb*32 + m32;
                a[mb] = *(const short8*)&As[rA][(lk ^ (rA & 7))*8];
            }
            #pragma unroll
            for (int nb = 0; nb < 2; ++nb){
                int rB = wn + nb*32 + m32;
                bfr[nb] = *(const short8*)&Bs[rB][(lk ^ (rB & 7))*8];
            }
            #pragma unroll
            for (int mb = 0; mb < 2; ++mb)
                #pragma unroll
                for (int nb = 0; nb < 2; ++nb)
                    acc[mb][nb] = __builtin_amdgcn_mfma_f32_32x32x16_bf16(a[mb], bfr[nb], acc[mb][nb], 0, 0, 0);
        }
    }
    // epilogue: per-column max/sum/sumsq over this block's 128 rows
    // C/D layout (verified m74/m101): col = lane&31; rows spread over regs+lane>>5 (reduction-invariant)
    __syncthreads();
    float* red = (float*)&As[0][0];
    #pragma unroll
    for (int nb = 0; nb < 2; ++nb){
        float mx = -INFINITY, s1 = 0.f, s2 = 0.f;
        #pragma unroll
        for (int mb = 0; mb < 2; ++mb)
            #pragma unroll
            for (int r = 0; r < 16; ++r){
                float v = acc[mb][nb][r];
                mx = fmaxf(mx, v); s1 += v; s2 = fmaf(v, v, s2);
            }
        mx = fmaxf(mx, __shfl_xor(mx, 32));
        s1 += __shfl_xor(s1, 32);
        s2 += __shfl_xor(s2, 32);
        if (lane < 32){
            int col = wn + nb*32 + m32;
            float* p = red + ((size_t)(w & 1) * 128 + col) * 3;
            p[0] = mx; p[1] = s1; p[2] = s2;
        }
    }
    __syncthreads();
    if (tid < 128){
        const float* p0 = red + (size_t)tid*3;
        const float* p1 = red + (size_t)(128 + tid)*3;
        float mx = fmaxf(p0[0], p1[0]);
        float s1 = p0[1] + p1[1];
        float s2 = p0[2] + p1[2];
        size_t pi = (size_t)blockIdx.x*1024 + o0 + tid;
        pmax[pi] = mx; psum[pi] = s1; psq[pi] = s2;
    }
}

__global__ void fin5_kernel(const float* __restrict__ pmax, const float* __restrict__ psum,
                            const float* __restrict__ psq,
                            const float* __restrict__ g, const float* __restrict__ bt,
                            float* __restrict__ out){
    int o = blockIdx.x*256 + threadIdx.x; // 1024 total
    float s1 = 0.f, s2 = 0.f;
    for (int r = 0; r < 256; ++r){
        s1 += psum[(size_t)r*1024 + o];
        s2 += psq [(size_t)r*1024 + o];
    }
    float m  = s1 / 32768.f;
    float v  = s2 / 32768.f - m*m;
    float is = rsqrtf(v + 1e-5f);
    float gg = g[o], bb2 = bt[o];
    for (int b = 0; b < 32; ++b){
        float mx = -INFINITY;
        #pragma unroll
        for (int ns = 0; ns < 8; ++ns) mx = fmaxf(mx, pmax[((size_t)b*8 + ns)*1024 + o]);
        float hn = (mx - m) * is * gg + bb2;
        out[(size_t)b*1024 + o] = lrelu(hn);
    }
}

extern "C" void kernel_launch(void* const* d_in, const int* in_sizes, int n_in,
                              void* d_out, int out_size, void* d_ws, size_t ws_size,
                              hipStream_t stream) {
    (void)in_sizes; (void)n_in; (void)out_size;
    const float* x  = (const float*)d_in[0];
    const float* W1 = (const float*)d_in[1];  const float* g1 = (const float*)d_in[2];  const float* b1 = (const float*)d_in[3];
    const float* W2 = (const float*)d_in[4];  const float* g2 = (const float*)d_in[5];  const float* b2 = (const float*)d_in[6];
    const float* W3 = (const float*)d_in[7];  const float* g3 = (const float*)d_in[8];  const float* b3 = (const float*)d_in[9];
    const float* W4 = (const float*)d_in[10]; const float* g4 = (const float*)d_in[11]; const float* b4 = (const float*)d_in[12];
    const float* W5 = (const float*)d_in[13]; const float* g5 = (const float*)d_in[14]; const float* b5 = (const float*)d_in[15];
    float* out = (float*)d_out;

    // ---- adaptive distance-chunk size based on workspace ----
    const size_t fixedBytes = (size_t)PTS*512*4 + (size_t)PTS*KNNK*4 + (size_t)PTS*4
                            + (size_t)64*2*256*4 + 2048*4 + 3*(size_t)256*1024*4
                            + (size_t)1024*512*2;            // ~74.2 MB
    int CB;
    if      (ws_size >= fixedBytes + (size_t)32*NN*NN*4) CB = 32;
    else if (ws_size >= fixedBytes + (size_t)16*NN*NN*4) CB = 16;
    else                                                 CB = 8;
    const size_t Rbytes = (size_t)CB*NN*NN*4;

    char* wsp = (char*)d_ws;
    float* cat    = (float*)wsp; wsp += (size_t)PTS*512*4;       // 67.1 MB
    char*  R      = wsp;         wsp += Rbytes;                  // CB MB-scaled shared region
    int*   idx    = (int*)  wsp; wsp += (size_t)PTS*KNNK*4;      // 2.6 MB
    float* xx     = (float*)wsp; wsp += (size_t)PTS*4;
    float* stats  = (float*)wsp; wsp += (size_t)64*2*256*4;
    float* mean   = (float*)wsp; wsp += 1024*4;
    float* invstd = (float*)wsp; wsp += 1024*4;
    float* pmax   = (float*)wsp; wsp += (size_t)256*1024*4;
    float* psum   = (float*)wsp; wsp += (size_t)256*1024*4;
    float* psq    = (float*)wsp; wsp += (size_t)256*1024*4;
    unsigned short* W5b = (unsigned short*)wsp; wsp += (size_t)1024*512*2;

    // region R aliases (sequentially dead):
    float* Dbuf  = (float*)R;
    float* G1    = (float*)R;
    float* GdS   = (float*)(R + (size_t)16*1024*1024);   // small-mode Gd (8192-pt groups / O<=128 full)
    float* GdB   = (float*)(R + (size_t)32*1024*1024);   // big-mode full-PTS O=256 Gd
    unsigned short* catB = (unsigned short*)R;

    const float cntE = (float)(PTS*KNNK);
    const int nch = 32 / CB;
    const bool bigG = (Rbytes >= (size_t)64*1024*1024);

    // ---- Layer 1: C=3 -> O=64, cat offset 0 ----
    sq_kernel<<<PTS/256, 256, 0, stream>>>(x, 3, 3, xx);
    for (int bc = 0; bc < nch; ++bc){
        dist_kernel<3><<<dim3(36,1,CB), 256, 0, stream>>>(x, 3, xx, Dbuf, bc*CB);
        topk_kernel<<<CB*1024/4, 256, 0, stream>>>(Dbuf, idx, bc*CB*1024);
    }
    hipMemsetAsync(stats, 0, 64*2*256*4, stream);
    gemmG_kernel<3,64><<<dim3(512,1), 256, 0, stream>>>(x, 3, W1, G1, GdS);
    gather_kernel<64><<<2048, 256, 0, stream>>>(G1, GdS, idx, 0, cat + 0, stats);
    fin_kernel<<<1, 64, 0, stream>>>(stats, 64, cntE, mean, invstd);
    apply_kernel<64><<<PTS*64/256, 256, 0, stream>>>(cat + 0, mean, invstd, g1, b1);

    // ---- Layer 2: C=64 -> O=64, cat offset 64 ----
    sq_kernel<<<PTS/256, 256, 0, stream>>>(cat + 0, 512, 64, xx);
    for (int bc = 0; bc < nch; ++bc){
        dist_kernel<64><<<dim3(36,1,CB), 256, 0, stream>>>(cat + 0, 512, xx, Dbuf, bc*CB);
        topk_kernel<<<CB*1024/4, 256, 0, stream>>>(Dbuf, idx, bc*CB*1024);
    }
    hipMemsetAsync(stats, 0, 64*2*256*4, stream);
    gemmG_kernel<64,64><<<dim3(512,1), 256, 0, stream>>>(cat + 0, 512, W2, G1, GdS);
    gather_kernel<64><<<2048, 256, 0, stream>>>(G1, GdS, idx, 0, cat + 64, stats);
    fin_kernel<<<1, 64, 0, stream>>>(stats, 64, cntE, mean, invstd);
    apply_kernel<64><<<PTS*64/256, 256, 0, stream>>>(cat + 64, mean, invstd, g2, b2);

    // ---- Layer 3: C=64 -> O=128, cat offset 128 ----
    sq_kernel<<<PTS/256, 256, 0, stream>>>(cat + 64, 512, 64, xx);
    for (int bc = 0; bc < nch; ++bc){
        dist_kernel<64><<<dim3(36,1,CB), 256, 0, stream>>>(cat + 64, 512, xx, Dbuf, bc*CB);
        topk_kernel<<<CB*1024/4, 256, 0, stream>>>(Dbuf, idx, bc*CB*1024);
    }
    hipMemsetAsync(stats, 0, 64*2*256*4, stream);
    gemmG_kernel<64,128><<<dim3(512,2), 256, 0, stream>>>(cat + 64, 512, W3, G1, GdS);
    gather_kernel<128><<<2048, 256, 0, stream>>>(G1, GdS, idx, 0, cat + 128, stats);
    fin_kernel<<<1, 128, 0, stream>>>(stats, 128, cntE, mean, invstd);
    apply_kernel<128><<<PTS*128/256, 256, 0, stream>>>(cat + 128, mean, invstd, g3, b3);

    // ---- Layer 4: C=128 -> O=256, cat offset 256 ----
    sq_kernel<<<PTS/256, 256, 0, stream>>>(cat + 128, 512, 128, xx);
    for (int bc = 0; bc < nch; ++bc){
        dist_kernel<128><<<dim3(36,1,CB), 256, 0, stream>>>(cat + 128, 512, xx, Dbuf, bc*CB);
        topk_kernel<<<CB*1024/4, 256, 0, stream>>>(Dbuf, idx, bc*CB*1024);
    }
    hipMemsetAsync(stats, 0, 64*2*256*4, stream);
    if (bigG){
        gemmG_kernel<128,256><<<dim3(512,4), 256, 0, stream>>>(cat + 128, 512, W4, G1, GdB);
        gather_kernel<256><<<2048, 256, 0, stream>>>(G1, GdB, idx, 0, cat + 256, stats);
    } else {
        for (int bg = 0; bg < 4; ++bg){
            gemmG_kernel<128,256><<<dim3(128,4), 256, 0, stream>>>(cat + 128 + (size_t)bg*8192*512, 512, W4, G1, GdS);
            gather_kernel<256><<<512, 256, 0, stream>>>(G1, GdS, idx, bg*8192, cat + 256, stats);
        }
    }
    fin_kernel<<<1, 256, 0, stream>>>(stats, 256, cntE, mean, invstd);
    apply_kernel<256><<<PTS*256/256, 256, 0, stream>>>(cat + 256, mean, invstd, g4, b4);

    // ---- Layer 5: bf16 MFMA GEMM with fused max/stats ----
    tob16_kernel<<<PTS*512/4/256, 256, 0, stream>>>(cat, catB, PTS*512/4);
    tob16_kernel<<<1024*512/4/256, 256, 0, stream>>>(W5, W5b, 1024*512/4);
    l5m_kernel<<<dim3(256, 8), 256, 0, stream>>>(catB, W5b, pmax, psum, psq);
    fin5_kernel<<<4, 256, 0, stream>>>(pmax, psum, psq, g5, b5, out);
}

// Round 7
// 1234.948 us; speedup vs baseline: 8.1645x; 1.0149x over previous
//
#include <hip/hip_runtime.h>
#include <math.h>

#define BB 32
#define NN 1024
#define KNNK 20
#define PTS (BB*NN)   // 32768

typedef __attribute__((ext_vector_type(8)))  short short8;
typedef __attribute__((ext_vector_type(4)))  float f32x4;
typedef __attribute__((ext_vector_type(16))) float f32x16;

__device__ __forceinline__ float lrelu(float v){ return v >= 0.f ? v : 0.2f*v; }

__device__ __forceinline__ unsigned short f2b(float x){
    union { float f; unsigned u; } c; c.f = x;
    unsigned r = c.u + 0x7FFFu + ((c.u >> 16) & 1u);
    return (unsigned short)(r >> 16);
}

// ---------------- squared norms per point ----------------
__global__ void sq_kernel(const float* __restrict__ x, int stride, int C, float* __restrict__ xx){
    int pn = blockIdx.x*256 + threadIdx.x;
    if (pn >= PTS) return;
    const float* r = x + (size_t)pn*stride;
    float s = 0.f;
    for (int c = 0; c < C; ++c){ float v = r[c]; s = fmaf(v, v, s); }
    xx[pn] = s;
}

// ---------------- distance GEMM, SYMMETRIC: upper-tri 128x128 tiles, 8x8/thread ----------------
template<int C>
__global__ void __launch_bounds__(256) dist_kernel(const float* __restrict__ x, int stride,
                                                   const float* __restrict__ xx,
                                                   float* __restrict__ D, int b0){
    constexpr int KC = (C < 32 ? C : 32);
    __shared__ float As[KC][132];
    __shared__ float Bs[KC][132];
    const int tid = threadIdx.x;
    int t = blockIdx.x, ti = 0;
    while (t >= 8 - ti){ t -= 8 - ti; ++ti; }
    const int tj = ti + t;
    const int i0 = ti*128, j0 = tj*128;
    const int bl = blockIdx.z;
    const int b  = b0 + bl;
    const float* xb = x + (size_t)b*NN*stride;
    const int rt = tid >> 4, ct = tid & 15;
    float acc[8][8] = {{0.f}};

    for (int kc = 0; kc < C; kc += KC){
        __syncthreads();
        if constexpr (KC % 4 == 0){
            for (int i = tid; i < 128*(KC/4); i += 256){
                int kq = i % (KC/4), rr = i / (KC/4);
                float4 va = *(const float4*)&xb[(size_t)(i0+rr)*stride + kc + kq*4];
                As[kq*4+0][rr]=va.x; As[kq*4+1][rr]=va.y; As[kq*4+2][rr]=va.z; As[kq*4+3][rr]=va.w;
                float4 vb = *(const float4*)&xb[(size_t)(j0+rr)*stride + kc + kq*4];
                Bs[kq*4+0][rr]=vb.x; Bs[kq*4+1][rr]=vb.y; Bs[kq*4+2][rr]=vb.z; Bs[kq*4+3][rr]=vb.w;
            }
        } else {
            for (int i = tid; i < 128*KC; i += 256){
                int k = i % KC, rr = i / KC;
                As[k][rr] = xb[(size_t)(i0+rr)*stride + kc + k];
                Bs[k][rr] = xb[(size_t)(j0+rr)*stride + kc + k];
            }
        }
        __syncthreads();
        #pragma unroll
        for (int k = 0; k < KC; ++k){
            float4 a0 = *(const float4*)&As[k][rt*8];
            float4 a1 = *(const float4*)&As[k][rt*8+4];
            float4 b0v= *(const float4*)&Bs[k][ct*8];
            float4 b1v= *(const float4*)&Bs[k][ct*8+4];
            float av[8]={a0.x,a0.y,a0.z,a0.w,a1.x,a1.y,a1.z,a1.w};
            float bw[8]={b0v.x,b0v.y,b0v.z,b0v.w,b1v.x,b1v.y,b1v.z,b1v.w};
            #pragma unroll
            for (int i = 0; i < 8; ++i)
                #pragma unroll
                for (int j = 0; j < 8; ++j)
                    acc[i][j] = fmaf(av[i], bw[j], acc[i][j]);
        }
    }
    const float* xxb = xx + b*NN;
    float xi[8], xj[8];
    #pragma unroll
    for (int i=0;i<8;++i) xi[i] = xxb[i0 + rt*8 + i];
    #pragma unroll
    for (int j=0;j<8;++j) xj[j] = xxb[j0 + ct*8 + j];
    #pragma unroll
    for (int i=0;i<8;++i){
        float4 d0, d1;
        d0.x = 2.f*acc[i][0] - xi[i] - xj[0];
        d0.y = 2.f*acc[i][1] - xi[i] - xj[1];
        d0.z = 2.f*acc[i][2] - xi[i] - xj[2];
        d0.w = 2.f*acc[i][3] - xi[i] - xj[3];
        d1.x = 2.f*acc[i][4] - xi[i] - xj[4];
        d1.y = 2.f*acc[i][5] - xi[i] - xj[5];
        d1.z = 2.f*acc[i][6] - xi[i] - xj[6];
        d1.w = 2.f*acc[i][7] - xi[i] - xj[7];
        float* drow = &D[((size_t)bl*NN + i0 + rt*8 + i)*NN + j0 + ct*8];
        *(float4*)drow = d0;
        *(float4*)(drow+4) = d1;
    }
    if (ti != tj){
        #pragma unroll
        for (int j=0;j<8;++j){
            float4 m0, m1;
            m0.x = 2.f*acc[0][j] - xj[j] - xi[0];
            m0.y = 2.f*acc[1][j] - xj[j] - xi[1];
            m0.z = 2.f*acc[2][j] - xj[j] - xi[2];
            m0.w = 2.f*acc[3][j] - xj[j] - xi[3];
            m1.x = 2.f*acc[4][j] - xj[j] - xi[4];
            m1.y = 2.f*acc[5][j] - xj[j] - xi[5];
            m1.z = 2.f*acc[6][j] - xj[j] - xi[6];
            m1.w = 2.f*acc[7][j] - xj[j] - xi[7];
            float* mrow = &D[((size_t)bl*NN + j0 + ct*8 + j)*NN + i0 + rt*8];
            *(float4*)mrow = m0;
            *(float4*)(mrow+4) = m1;
        }
    }
}

// ---------------- top-k via radix bisection + ballot compaction (exact set, exact ties) ----
// wave per row. Selects {20 largest by (value desc, index asc)} — identical set to iterative
// argmax: all keys > t plus first (20-c) equals of t in ascending global index order.
__global__ void __launch_bounds__(256) topk_kernel(const float* __restrict__ D,
                                                   int* __restrict__ idxout, int baseRow){
    const int tid = threadIdx.x;
    const int wv = tid >> 6, lane = tid & 63;
    const int rid = blockIdx.x*4 + wv;
    const float* drow = D + (size_t)rid * NN;
    unsigned u[16];
    #pragma unroll
    for (int i = 0; i < 16; ++i){
        unsigned bits = __float_as_uint(drow[i*64 + lane]);
        unsigned m = (bits & 0x80000000u) ? 0xFFFFFFFFu : 0x80000000u;  // monotone map
        u[i] = bits ^ m;
    }
    // bisect for t = 20th-largest key (max t with count(>= t) >= 20)
    unsigned t = 0u;
    for (int b = 31; b >= 0; --b){
        unsigned cand = t | (1u << b);
        int cnt = 0;
        #pragma unroll
        for (int i = 0; i < 16; ++i)
            cnt += (int)__popcll(__ballot(u[i] >= cand));
        if (cnt >= KNNK) t = cand;
    }
    const unsigned long long lt = (lane == 0) ? 0ull : ((~0ull) >> (64 - lane));
    int* orow = idxout + ((size_t)baseRow + rid) * KNNK;
    int cbase = 0;
    // emit all strictly greater (count <= 19 by construction of t)
    #pragma unroll
    for (int i = 0; i < 16; ++i){
        bool gt2 = (u[i] > t);
        unsigned long long mask = __ballot(gt2);
        if (gt2) orow[cbase + (int)__popcll(mask & lt)] = i*64 + lane;
        cbase += (int)__popcll(mask);
    }
    // fill remaining slots with equals in ascending global index (i asc, lane asc == j asc)
    for (int i = 0; i < 16; ++i){
        if (cbase >= KNNK) break;
        bool eq = (u[i] == t);
        unsigned long long mask = __ballot(eq);
        int pos = cbase + (int)__popcll(mask & lt);
        if (eq && pos < KNNK) orow[pos] = i*64 + lane;
        cbase += (int)__popcll(mask);
    }
}

// ---------------- G GEMMs: G1 = X @ W[:, :C]^T ; Gd = X @ (W[:,C:]-W[:, :C])^T ----------------
template<int C, int O>
__global__ void __launch_bounds__(256) gemmG_kernel(const float* __restrict__ x, int stride,
                                                    const float* __restrict__ W,
                                                    float* __restrict__ G1, float* __restrict__ Gd){
    constexpr int KC = (C < 32 ? C : 32);
    __shared__ float Xl [KC][68];
    __shared__ float W1l[KC][68];
    __shared__ float W2l[KC][68];
    const int tid = threadIdx.x;
    const int r0 = blockIdx.x * 64;
    const int o0 = blockIdx.y * 64;
    const int rt = tid & 15, ct = tid >> 4;

    float a1[4][4] = {{0.f}}, a2[4][4] = {{0.f}};
    for (int kc = 0; kc < C; kc += KC){
        __syncthreads();
        for (int i = tid; i < KC*64; i += 256){
            int k = i % KC, rr = i / KC;
            Xl [k][rr] = x[(size_t)(r0+rr)*stride + kc + k];
            W1l[k][rr] = W[(size_t)(o0+rr)*(2*C) + kc + k];
            W2l[k][rr] = W[(size_t)(o0+rr)*(2*C) + C + kc + k];
        }
        __syncthreads();
        #pragma unroll
        for (int k = 0; k < KC; ++k){
            float4 xa = *(const float4*)&Xl [k][rt*4];
            float4 w1 = *(const float4*)&W1l[k][ct*4];
            float4 w2 = *(const float4*)&W2l[k][ct*4];
            float xv[4] = {xa.x, xa.y, xa.z, xa.w};
            #pragma unroll
            for (int i = 0; i < 4; ++i){
                a1[i][0] = fmaf(xv[i], w1.x, a1[i][0]);
                a1[i][1] = fmaf(xv[i], w1.y, a1[i][1]);
                a1[i][2] = fmaf(xv[i], w1.z, a1[i][2]);
                a1[i][3] = fmaf(xv[i], w1.w, a1[i][3]);
                a2[i][0] = fmaf(xv[i], w2.x, a2[i][0]);
                a2[i][1] = fmaf(xv[i], w2.y, a2[i][1]);
                a2[i][2] = fmaf(xv[i], w2.z, a2[i][2]);
                a2[i][3] = fmaf(xv[i], w2.w, a2[i][3]);
            }
        }
    }
    #pragma unroll
    for (int i = 0; i < 4; ++i){
        size_t row = (size_t)(r0 + rt*4 + i);
        float4 g1v = make_float4(a1[i][0], a1[i][1], a1[i][2], a1[i][3]);
        float4 gdv = make_float4(a2[i][0]-a1[i][0], a2[i][1]-a1[i][1],
                                 a2[i][2]-a1[i][2], a2[i][3]-a1[i][3]);
        *(float4*)&G1[row*O + o0 + ct*4] = g1v;
        *(float4*)&Gd[row*O + o0 + ct*4] = gdv;
    }
}

// ---------------- gather (float4): per (point, 4 cols) max/sum/sumsq over k ----------------
template<int O>
__global__ void __launch_bounds__(256) gather_kernel(const float* __restrict__ G1,
                                                     const float* __restrict__ Gd,
                                                     const int* __restrict__ idxg, int bgbase,
                                                     float* __restrict__ catslice,
                                                     float* __restrict__ stats){
    constexpr int OG = O/4;
    constexpr int PP = 256/OG;
    constexpr int NP = 16;
    __shared__ int nbs[NP][KNNK];
    const int tid = threadIdx.x;
    const int p0 = blockIdx.x * NP;
    for (int i = tid; i < NP*KNNK; i += 256){
        int pp = i / KNNK, kk = i - pp*KNNK;
        int pl = p0 + pp;
        nbs[pp][kk] = ((pl >> 10) << 10) + idxg[(size_t)(bgbase + pl)*KNNK + kk];
    }
    __syncthreads();
    const int o4 = (tid % OG)*4;
    const int pq = tid / OG;
    float S1[4] = {0.f,0.f,0.f,0.f}, S2[4] = {0.f,0.f,0.f,0.f};
    for (int pp = pq; pp < NP; pp += PP){
        int pl = p0 + pp;
        float4 dv = *(const float4*)&Gd[(size_t)pl*O + o4];
        float d[4] = {dv.x, dv.y, dv.z, dv.w};
        float mx[4] = {-INFINITY,-INFINITY,-INFINITY,-INFINITY};
        float ls[4] = {0.f,0.f,0.f,0.f}, lq[4] = {0.f,0.f,0.f,0.f};
        #pragma unroll
        for (int kk = 0; kk < KNNK; ++kk){
            float4 gv = *(const float4*)&G1[(size_t)nbs[pp][kk]*O + o4];
            float ga[4] = {gv.x, gv.y, gv.z, gv.w};
            #pragma unroll
            for (int c = 0; c < 4; ++c){
                mx[c] = fmaxf(mx[c], ga[c]);
                ls[c] += ga[c];
                lq[c] = fmaf(ga[c], ga[c], lq[c]);
            }
        }
        float4 outv;
        float* op = &outv.x;
        #pragma unroll
        for (int c = 0; c < 4; ++c){
            S1[c] += ls[c] + 20.f*d[c];
            S2[c] += lq[c] + 2.f*d[c]*ls[c] + 20.f*d[c]*d[c];
            op[c] = mx[c] + d[c];
        }
        *(float4*)&catslice[(size_t)(bgbase + pl)*512 + o4] = outv;
    }
    int rep = blockIdx.x & 63;
    #pragma unroll
    for (int c = 0; c < 4; ++c){
        atomicAdd(&stats[rep*2*O + o4 + c],     S1[c]);
        atomicAdd(&stats[rep*2*O + O + o4 + c], S2[c]);
    }
}

// ---------------- finalize BN stats ----------------
__global__ void fin_kernel(const float* __restrict__ stats, int O, float cnt,
                           float* __restrict__ mean, float* __restrict__ invstd){
    int o = threadIdx.x;
    if (o >= O) return;
    float s1 = 0.f, s2 = 0.f;
    for (int r = 0; r < 64; ++r){
        s1 += stats[r*2*O + o];
        s2 += stats[r*2*O + O + o];
    }
    float m = s1 / cnt;
    float v = s2 / cnt - m*m;
    mean[o] = m;
    invstd[o] = rsqrtf(v + 1e-5f);
}

// ---------------- apply BN+LReLU in place on cat slice ----------------
template<int O>
__global__ void apply_kernel(float* __restrict__ catslice,
                             const float* __restrict__ mean, const float* __restrict__ invstd,
                             const float* __restrict__ g, const float* __restrict__ bt){
    int i = blockIdx.x*256 + threadIdx.x;
    int pn = i / O, o = i - pn*O;
    float* p = &catslice[(size_t)pn*512 + o];
    float hn = (*p - mean[o]) * invstd[o] * g[o] + bt[o];
    *p = lrelu(hn);
}

// ---------------- fp32 -> bf16 conversion (4 elems/thread) ----------------
__global__ void tob16_kernel(const float* __restrict__ src, unsigned short* __restrict__ dst, int n4){
    int i = blockIdx.x*256 + threadIdx.x;
    if (i >= n4) return;
    float4 v = *(const float4*)&src[(size_t)i*4];
    ushort4 o;
    o.x = f2b(v.x); o.y = f2b(v.y); o.z = f2b(v.z); o.w = f2b(v.w);
    *(ushort4*)&dst[(size_t)i*4] = o;
}

// ---------------- layer 5 MFMA: 32x32x16 frags, 64x64/wave, 128x128/block ----------------
__global__ void __launch_bounds__(256) l5m_kernel(const unsigned short* __restrict__ Am,
                                                  const unsigned short* __restrict__ Bm,
                                                  float* __restrict__ pmax,
                                                  float* __restrict__ psum,
                                                  float* __restrict__ psq){
    __shared__ __align__(16) unsigned short As[128][64];
    __shared__ __align__(16) unsigned short Bs[128][64];
    const int tid = threadIdx.x;
    const int r0 = blockIdx.x * 128;
    const int o0 = blockIdx.y * 128;
    const int w = tid >> 6, lane = tid & 63;
    const int m32 = lane & 31, kh = lane >> 5;
    const int wm = (w & 1) * 64;
    const int wn = (w >> 1) * 64;

    f32x16 acc[2][2];
    #pragma unroll
    for (int i=0;i<2;++i)
        #pragma unroll
        for (int j=0;j<2;++j)
            #pragma unroll
            for (int r=0;r<16;++r) acc[i][j][r] = 0.f;

    for (int kc = 0; kc < 512; kc += 64){
        __syncthreads();
        #pragma unroll
        for (int t = 0; t < 4; ++t){
            int i = tid + t*256;
            int rr = i >> 3, ch = i & 7;
            int sl = ch ^ (rr & 7);
            *(uint4*)&As[rr][sl*8] = *(const uint4*)&Am[(size_t)(r0+rr)*512 + kc + ch*8];
            *(uint4*)&Bs[rr][sl*8] = *(const uint4*)&Bm[(size_t)(o0+rr)*512 + kc + ch*8];
        }
        __syncthreads();
        #pragma unroll
        for (int q = 0; q < 4; ++q){
            int lk = q*2 + kh;
            short8 a[2], bfr[2];
            #pragma unroll
            for (int mb = 0; mb < 2; ++mb){
                int rA = wm + mb*32 + m32;
                a[mb] = *(const short8*)&As[rA][(lk ^ (rA & 7))*8];
            }
            #pragma unroll
            for (int nb = 0; nb < 2; ++nb){
                int rB = wn + nb*32 + m32;
                bfr[nb] = *(const short8*)&Bs[rB][(lk ^ (rB & 7))*8];
            }
            #pragma unroll
            for (int mb = 0; mb < 2; ++mb)
                #pragma unroll
                for (int nb = 0; nb < 2; ++nb)
                    acc[mb][nb] = __builtin_amdgcn_mfma_f32_32x32x16_bf16(a[mb], bfr[nb], acc[mb][nb], 0, 0, 0);
        }
    }
    __syncthreads();
    float* red = (float*)&As[0][0];
    #pragma unroll
    for (int nb = 0; nb < 2; ++nb){
        float mx = -INFINITY, s1 = 0.f, s2 = 0.f;
        #pragma unroll
        for (int mb = 0; mb < 2; ++mb)
            #pragma unroll
            for (int r = 0; r < 16; ++r){
                float v = acc[mb][nb][r];
                mx = fmaxf(mx, v); s1 += v; s2 = fmaf(v, v, s2);
            }
        mx = fmaxf(mx, __shfl_xor(mx, 32));
        s1 += __shfl_xor(s1, 32);
        s2 += __shfl_xor(s2, 32);
        if (lane < 32){
            int col = wn + nb*32 + m32;
            float* p = red + ((size_t)(w & 1) * 128 + col) * 3;
            p[0] = mx; p[1] = s1; p[2] = s2;
        }
    }
    __syncthreads();
    if (tid < 128){
        const float* p0 = red + (size_t)tid*3;
        const float* p1 = red + (size_t)(128 + tid)*3;
        float mx = fmaxf(p0[0], p1[0]);
        float s1 = p0[1] + p1[1];
        float s2 = p0[2] + p1[2];
        size_t pi = (size_t)blockIdx.x*1024 + o0 + tid;
        pmax[pi] = mx; psum[pi] = s1; psq[pi] = s2;
    }
}

__global__ void fin5_kernel(const float* __restrict__ pmax, const float* __restrict__ psum,
                            const float* __restrict__ psq,
                            const float* __restrict__ g, const float* __restrict__ bt,
                            float* __restrict__ out){
    int o = blockIdx.x*256 + threadIdx.x; // 1024 total
    float s1 = 0.f, s2 = 0.f;
    for (int r = 0; r < 256; ++r){
        s1 += psum[(size_t)r*1024 + o];
        s2 += psq [(size_t)r*1024 + o];
    }
    float m  = s1 / 32768.f;
    float v  = s2 / 32768.f - m*m;
    float is = rsqrtf(v + 1e-5f);
    float gg = g[o], bb2 = bt[o];
    for (int b = 0; b < 32; ++b){
        float mx = -INFINITY;
        #pragma unroll
        for (int ns = 0; ns < 8; ++ns) mx = fmaxf(mx, pmax[((size_t)b*8 + ns)*1024 + o]);
        float hn = (mx - m) * is * gg + bb2;
        out[(size_t)b*1024 + o] = lrelu(hn);
    }
}

extern "C" void kernel_launch(void* const* d_in, const int* in_sizes, int n_in,
                              void* d_out, int out_size, void* d_ws, size_t ws_size,
                              hipStream_t stream) {
    (void)in_sizes; (void)n_in; (void)out_size;
    const float* x  = (const float*)d_in[0];
    const float* W1 = (const float*)d_in[1];  const float* g1 = (const float*)d_in[2];  const float* b1 = (const float*)d_in[3];
    const float* W2 = (const float*)d_in[4];  const float* g2 = (const float*)d_in[5];  const float* b2 = (const float*)d_in[6];
    const float* W3 = (const float*)d_in[7];  const float* g3 = (const float*)d_in[8];  const float* b3 = (const float*)d_in[9];
    const float* W4 = (const float*)d_in[10]; const float* g4 = (const float*)d_in[11]; const float* b4 = (const float*)d_in[12];
    const float* W5 = (const float*)d_in[13]; const float* g5 = (const float*)d_in[14]; const float* b5 = (const float*)d_in[15];
    float* out = (float*)d_out;

    const size_t fixedBytes = (size_t)PTS*512*4 + (size_t)PTS*KNNK*4 + (size_t)PTS*4
                            + (size_t)64*2*256*4 + 2048*4 + 3*(size_t)256*1024*4
                            + (size_t)1024*512*2;
    int CB;
    if      (ws_size >= fixedBytes + (size_t)32*NN*NN*4) CB = 32;
    else if (ws_size >= fixedBytes + (size_t)16*NN*NN*4) CB = 16;
    else                                                 CB = 8;
    const size_t Rbytes = (size_t)CB*NN*NN*4;

    char* wsp = (char*)d_ws;
    float* cat    = (float*)wsp; wsp += (size_t)PTS*512*4;
    char*  R      = wsp;         wsp += Rbytes;
    int*   idx    = (int*)  wsp; wsp += (size_t)PTS*KNNK*4;
    float* xx     = (float*)wsp; wsp += (size_t)PTS*4;
    float* stats  = (float*)wsp; wsp += (size_t)64*2*256*4;
    float* mean   = (float*)wsp; wsp += 1024*4;
    float* invstd = (float*)wsp; wsp += 1024*4;
    float* pmax   = (float*)wsp; wsp += (size_t)256*1024*4;
    float* psum   = (float*)wsp; wsp += (size_t)256*1024*4;
    float* psq    = (float*)wsp; wsp += (size_t)256*1024*4;
    unsigned short* W5b = (unsigned short*)wsp; wsp += (size_t)1024*512*2;

    float* Dbuf  = (float*)R;
    float* G1    = (float*)R;
    float* GdS   = (float*)(R + (size_t)16*1024*1024);
    float* GdB   = (float*)(R + (size_t)32*1024*1024);
    unsigned short* catB = (unsigned short*)R;

    const float cntE = (float)(PTS*KNNK);
    const int nch = 32 / CB;
    const bool bigG = (Rbytes >= (size_t)64*1024*1024);

    // ---- Layer 1: C=3 -> O=64 ----
    sq_kernel<<<PTS/256, 256, 0, stream>>>(x, 3, 3, xx);
    for (int bc = 0; bc < nch; ++bc){
        dist_kernel<3><<<dim3(36,1,CB), 256, 0, stream>>>(x, 3, xx, Dbuf, bc*CB);
        topk_kernel<<<CB*1024/4, 256, 0, stream>>>(Dbuf, idx, bc*CB*1024);
    }
    hipMemsetAsync(stats, 0, 64*2*256*4, stream);
    gemmG_kernel<3,64><<<dim3(512,1), 256, 0, stream>>>(x, 3, W1, G1, GdS);
    gather_kernel<64><<<2048, 256, 0, stream>>>(G1, GdS, idx, 0, cat + 0, stats);
    fin_kernel<<<1, 64, 0, stream>>>(stats, 64, cntE, mean, invstd);
    apply_kernel<64><<<PTS*64/256, 256, 0, stream>>>(cat + 0, mean, invstd, g1, b1);

    // ---- Layer 2: C=64 -> O=64 ----
    sq_kernel<<<PTS/256, 256, 0, stream>>>(cat + 0, 512, 64, xx);
    for (int bc = 0; bc < nch; ++bc){
        dist_kernel<64><<<dim3(36,1,CB), 256, 0, stream>>>(cat + 0, 512, xx, Dbuf, bc*CB);
        topk_kernel<<<CB*1024/4, 256, 0, stream>>>(Dbuf, idx, bc*CB*1024);
    }
    hipMemsetAsync(stats, 0, 64*2*256*4, stream);
    gemmG_kernel<64,64><<<dim3(512,1), 256, 0, stream>>>(cat + 0, 512, W2, G1, GdS);
    gather_kernel<64><<<2048, 256, 0, stream>>>(G1, GdS, idx, 0, cat + 64, stats);
    fin_kernel<<<1, 64, 0, stream>>>(stats, 64, cntE, mean, invstd);
    apply_kernel<64><<<PTS*64/256, 256, 0, stream>>>(cat + 64, mean, invstd, g2, b2);

    // ---- Layer 3: C=64 -> O=128 ----
    sq_kernel<<<PTS/256, 256, 0, stream>>>(cat + 64, 512, 64, xx);
    for (int bc = 0; bc < nch; ++bc){
        dist_kernel<64><<<dim3(36,1,CB), 256, 0, stream>>>(cat + 64, 512, xx, Dbuf, bc*CB);
        topk_kernel<<<CB*1024/4, 256, 0, stream>>>(Dbuf, idx, bc*CB*1024);
    }
    hipMemsetAsync(stats, 0, 64*2*256*4, stream);
    gemmG_kernel<64,128><<<dim3(512,2), 256, 0, stream>>>(cat + 64, 512, W3, G1, GdS);
    gather_kernel<128><<<2048, 256, 0, stream>>>(G1, GdS, idx, 0, cat + 128, stats);
    fin_kernel<<<1, 128, 0, stream>>>(stats, 128, cntE, mean, invstd);
    apply_kernel<128><<<PTS*128/256, 256, 0, stream>>>(cat + 128, mean, invstd, g3, b3);

    // ---- Layer 4: C=128 -> O=256 ----
    sq_kernel<<<PTS/256, 256, 0, stream>>>(cat + 128, 512, 128, xx);
    for (int bc = 0; bc < nch; ++bc){
        dist_kernel<128><<<dim3(36,1,CB), 256, 0, stream>>>(cat + 128, 512, xx, Dbuf, bc*CB);
        topk_kernel<<<CB*1024/4, 256, 0, stream>>>(Dbuf, idx, bc*CB*1024);
    }
    hipMemsetAsync(stats, 0, 64*2*256*4, stream);
    if (bigG){
        gemmG_kernel<128,256><<<dim3(512,4), 256, 0, stream>>>(cat + 128, 512, W4, G1, GdB);
        gather_kernel<256><<<2048, 256, 0, stream>>>(G1, GdB, idx, 0, cat + 256, stats);
    } else {
        for (int bg = 0; bg < 4; ++bg){
            gemmG_kernel<128,256><<<dim3(128,4), 256, 0, stream>>>(cat + 128 + (size_t)bg*8192*512, 512, W4, G1, GdS);
            gather_kernel<256><<<512, 256, 0, stream>>>(G1, GdS, idx, bg*8192, cat + 256, stats);
        }
    }
    fin_kernel<<<1, 256, 0, stream>>>(stats, 256, cntE, mean, invstd);
    apply_kernel<256><<<PTS*256/256, 256, 0, stream>>>(cat + 256, mean, invstd, g4, b4);

    // ---- Layer 5: bf16 MFMA GEMM with fused max/stats ----
    tob16_kernel<<<PTS*512/4/256, 256, 0, stream>>>(cat, catB, PTS*512/4);
    tob16_kernel<<<1024*512/4/256, 256, 0, stream>>>(W5, W5b, 1024*512/4);
    l5m_kernel<<<dim3(256, 8), 256, 0, stream>>>(catB, W5b, pmax, psum, psq);
    fin5_kernel<<<4, 256, 0, stream>>>(pmax, psum, psq, g5, b5, out);
}